// Round 12
// baseline (707.708 us; speedup 1.0000x reference)
//
#include <hip/hip_runtime.h>
#include <math.h>

// PhiDecoderLayer on MI355X. B=2, S=2048, E=2048, MLP=8192, fp32 in/out.
// Round 12: 128x256 tile, BK=32, 48 KiB LDS, __launch_bounds__(512,4) ->
// 2 independent blocks/CU (the m114/m97 cross-block overlap mechanism,
// which 1-block/CU 256^2 structurally lacks). Same proven loop skeleton:
// rd -> MFMA -> bar -> stage(kt+2->cur) -> vmcnt(3) -> bar. One kernel for
// all six MFMA GEMMs (QKV, scores, PV, attn-out, mlp1, mlp2).

#define SEQ 2048
#define EMB 2048
#define MLPD 8192

typedef __attribute__((ext_vector_type(8))) short short8;
typedef __attribute__((ext_vector_type(4))) float floatx4;
typedef unsigned short ushort;

__device__ __forceinline__ short f2bf(float f) {
  union { float f; unsigned u; } v; v.f = f;
  unsigned r = v.u + 0x7FFFu + ((v.u >> 16) & 1u);
  return (short)(r >> 16);
}

// async global->LDS, 16B per lane. LDS dest = wave-uniform base + lane*16.
__device__ __forceinline__ void gload16(const ushort* g, const ushort* l) {
  __builtin_amdgcn_global_load_lds(
      (__attribute__((address_space(1))) void*)g,
      (__attribute__((address_space(3))) void*)(unsigned)(unsigned long)l,
      16, 0, 0);
}

enum { EPI_QKV = 0, EPI_SCORES = 1, EPI_PV = 2, EPI_GELU = 4 };

// ============================================================================
// 128x256 tile, BK=32, 8 waves (2Mx4N), per-wave 64x64 output (acc 4x4).
// LDS 48 KiB: buf(2) x [A:128x32 | B:256x32] bf16. Row = 64B = 4 granules;
// swizzle: LDS granule g of row r holds global granule g^(r&3) (2-way banks,
// free). Per K-step kt (cur CB = buf(kt&1)):
//   rd A(4)+B(4) ; 16 MFMA (reads drain into MFMA via counted lgkm)
//   BARR  (all waves' reads of CB complete)
//   STG(kt+2 -> CB, 3 gloads) ; vmcnt(3) (drains kt+1) ; BARR
// 2 blocks/CU provide cross-block pipe overlap at every barrier.
// ============================================================================
template<int EPI>
__global__ __launch_bounds__(512, 4)
void gemm128(const ushort* __restrict__ A, const ushort* __restrict__ B,
             const float* __restrict__ bias, void* __restrict__ Cp,
             int N, int K, int lda, int ldb, int ldc,
             long sA, long sB, long sC, float scale)
{
  extern __shared__ ushort lds[];   // 24576 ushorts = 48 KiB
  const int t = threadIdx.x;
  const int lane = t & 63, w = t >> 6;
  const int wm = w >> 2, wn = w & 3;
  const long bm = (long)blockIdx.y * 128;
  const long bn = (long)blockIdx.x * 256;
  A += (long)blockIdx.z * sA;
  B += (long)blockIdx.z * sB;

  // staging geometry: wave w covers 16 rows per gload; lane -> row w*16 +
  // (lane>>2), granule (lane&3) pre-swizzled by row&3.
  const int grow = (w << 4) + (lane >> 2);
  const int gcol = (lane & 3) ^ ((lane >> 2) & 3);
  const ushort* Ag  = A + (bm + grow) * (long)lda + gcol * 8;
  const ushort* Bg  = B + (bn + grow) * (long)ldb + gcol * 8;
  const ushort* Bg2 = B + (bn + 128 + grow) * (long)ldb + gcol * 8;
  const int lwA  = (w << 9);          // A region + wave slot (ushorts)
  const int lwB  = 4096 + (w << 9);   // B rows 0..127
  const int lwB2 = 8192 + (w << 9);   // B rows 128..255

#define STG(CB, KK) do {                                     \
    gload16(Ag  + (KK), lds + (CB) + lwA);                   \
    gload16(Bg  + (KK), lds + (CB) + lwB);                   \
    gload16(Bg2 + (KK), lds + (CB) + lwB2); } while (0)

  // read geometry: row*32 ushorts + swizzled granule
  const int l15 = lane & 15, q = lane >> 4;
  const int kx = (q ^ (l15 & 3)) << 3;
  const int ar = ((wm << 6) + l15) * 32 + kx;          // A: wm*64 rows
  const int br = 4096 + ((wn << 6) + l15) * 32 + kx;   // B: wn*64 rows

  floatx4 acc[4][4];
#pragma unroll
  for (int m = 0; m < 4; ++m)
#pragma unroll
    for (int n = 0; n < 4; ++n) acc[m][n] = (floatx4)0.0f;

  short8 a[4], b[4];

#define LDS8(IDX) (*(const short8*)&lds[IDX])
#define BARR() __builtin_amdgcn_s_barrier()

#define ITER(CB, KS) do {                                                 \
    _Pragma("unroll") for (int mf = 0; mf < 4; ++mf)                      \
      a[mf] = LDS8((CB) + ar + mf * 512);                                 \
    _Pragma("unroll") for (int nf = 0; nf < 4; ++nf)                      \
      b[nf] = LDS8((CB) + br + nf * 512);                                 \
    __builtin_amdgcn_s_setprio(1);                                        \
    _Pragma("unroll") for (int mf = 0; mf < 4; ++mf)                      \
      _Pragma("unroll") for (int nf = 0; nf < 4; ++nf)                    \
        acc[mf][nf] = __builtin_amdgcn_mfma_f32_16x16x32_bf16(            \
            a[mf], b[nf], acc[mf][nf], 0, 0, 0);                          \
    __builtin_amdgcn_s_setprio(0);                                        \
    BARR();                                                               \
    STG(CB, KS);                                                          \
    asm volatile("s_waitcnt vmcnt(3)" ::: "memory");                      \
    BARR();                                                               \
  } while (0)

  const int NT = K >> 5;  // K-steps of 32; >=32 and even for all shapes

  // ---- prologue: k0 -> buf0, k1 -> buf1; certify k0 ----
  STG(0, 0);
  STG(12288, 32);
  asm volatile("s_waitcnt vmcnt(3)" ::: "memory");
  BARR();

  for (int kt = 0; kt < NT; kt += 2) {
    const int k2 = ((kt + 2 < NT) ? kt + 2 : NT - 1) << 5;  // clamped tail
    const int k3 = ((kt + 3 < NT) ? kt + 3 : NT - 1) << 5;
    ITER(0,     k2);   // k-step kt   (buf0)
    ITER(12288, k3);   // k-step kt+1 (buf1)
  }
  asm volatile("s_waitcnt vmcnt(0)" ::: "memory");   // drain before epilogue
#undef ITER
#undef LDS8
#undef STG

  // ---- epilogue: C/D map col=lane&15, row=(lane>>4)*4+i ----
  const int lq = lane >> 4;
#pragma unroll
  for (int mf = 0; mf < 4; ++mf) {
#pragma unroll
    for (int nf = 0; nf < 4; ++nf) {
#pragma unroll
      for (int i = 0; i < 4; ++i) {
        const long r = bm + wm * 64 + mf * 16 + lq * 4 + i;
        const long c = bn + wn * 64 + nf * 16 + l15;
        float val = acc[mf][nf][i];
        if constexpr (EPI == EPI_QKV) {
          val += bias[c];
          ((ushort*)Cp)[r * (long)ldc + c] = (ushort)f2bf(val);
        } else if constexpr (EPI == EPI_SCORES) {  // raw f32 (scaled)
          ((float*)Cp)[(long)blockIdx.z * sC + r * (long)ldc + c] = val * scale;
        } else if constexpr (EPI == EPI_PV) {
          ((ushort*)Cp)[(long)blockIdx.z * sC + r * (long)ldc + c] = (ushort)f2bf(val);
        } else {  // EPI_GELU exact
          val += bias[c];
          float g = 0.5f * val * (1.0f + erff(val * 0.70710678118f));
          ((ushort*)Cp)[r * (long)ldc + c] = (ushort)f2bf(g);
        }
      }
    }
  }
}

// out = p0 + p1 + bias + res  (f32, 8 elems/thread, N=2048 columns)
__global__ __launch_bounds__(256)
void reduce2(const float* __restrict__ p0, const float* __restrict__ p1,
             const float* __restrict__ bias, const float* __restrict__ res,
             float* __restrict__ out)
{
  const long i = ((long)blockIdx.x * 256 + threadIdx.x) * 8;
  const int c = (int)(i & 2047);
  float4 a0 = *(const float4*)(p0 + i),  a1 = *(const float4*)(p0 + i + 4);
  float4 q0 = *(const float4*)(p1 + i),  q1 = *(const float4*)(p1 + i + 4);
  float4 r0 = *(const float4*)(res + i), r1 = *(const float4*)(res + i + 4);
  float4 b0 = *(const float4*)(bias + c), b1 = *(const float4*)(bias + c + 4);
  float4 o0 = {a0.x + q0.x + r0.x + b0.x, a0.y + q0.y + r0.y + b0.y,
               a0.z + q0.z + r0.z + b0.z, a0.w + q0.w + r0.w + b0.w};
  float4 o1 = {a1.x + q1.x + r1.x + b1.x, a1.y + q1.y + r1.y + b1.y,
               a1.z + q1.z + r1.z + b1.z, a1.w + q1.w + r1.w + b1.w};
  *(float4*)(out + i) = o0;
  *(float4*)(out + i + 4) = o1;
}

__global__ __launch_bounds__(256)
void cvt8(const float* __restrict__ s, ushort* __restrict__ d) {
  const long i = ((long)blockIdx.x * 256 + threadIdx.x) * 8;
  float4 a = *reinterpret_cast<const float4*>(s + i);
  float4 b = *reinterpret_cast<const float4*>(s + i + 4);
  short8 v;
  v[0] = f2bf(a.x); v[1] = f2bf(a.y); v[2] = f2bf(a.z); v[3] = f2bf(a.w);
  v[4] = f2bf(b.x); v[5] = f2bf(b.y); v[6] = f2bf(b.z); v[7] = f2bf(b.w);
  *reinterpret_cast<short8*>(d + i) = v;
}

__global__ __launch_bounds__(256)
void concat3(const float* __restrict__ b0, const float* __restrict__ b1,
             const float* __restrict__ b2, float* __restrict__ dst) {
  const int i = blockIdx.x * 256 + threadIdx.x;
  dst[i] = (i < 2048) ? b0[i] : (i < 4096) ? b1[i - 2048] : b2[i - 4096];
}

__global__ __launch_bounds__(256)
void transpose_v(const ushort* __restrict__ qkv, ushort* __restrict__ vT) {
  __shared__ ushort tile[32][33];
  const int b = blockIdx.z;
  const int s0 = blockIdx.x * 32, e0 = blockIdx.y * 32;
  const int tx = threadIdx.x & 31, ty = threadIdx.x >> 5;
#pragma unroll
  for (int i = 0; i < 4; ++i) {
    const long s = (long)b * SEQ + s0 + ty + i * 8;
    tile[ty + i * 8][tx] = qkv[s * 6144 + 4096 + e0 + tx];
  }
  __syncthreads();
#pragma unroll
  for (int i = 0; i < 4; ++i) {
    const long e = (long)b * SEQ + e0 + ty + i * 8;
    vT[e * SEQ + s0 + tx] = tile[tx][ty + i * 8];
  }
}

__global__ __launch_bounds__(256)
void softmax_rows(const float* __restrict__ S, ushort* __restrict__ P) {
  const long row = blockIdx.x;
  const float* src = S + row * 2048;
  const int t = threadIdx.x, lane = t & 63, wid = t >> 6;
  float4 a = *reinterpret_cast<const float4*>(src + t * 8);
  float4 b = *reinterpret_cast<const float4*>(src + t * 8 + 4);
  float v[8] = {a.x, a.y, a.z, a.w, b.x, b.y, b.z, b.w};
  float m = v[0];
#pragma unroll
  for (int i = 1; i < 8; ++i) m = fmaxf(m, v[i]);
#pragma unroll
  for (int o = 32; o; o >>= 1) m = fmaxf(m, __shfl_xor(m, o));
  __shared__ float rm[4], rs[4];
  if (!lane) rm[wid] = m;
  __syncthreads();
  m = fmaxf(fmaxf(rm[0], rm[1]), fmaxf(rm[2], rm[3]));
  float e[8], s = 0.f;
#pragma unroll
  for (int i = 0; i < 8; ++i) { e[i] = __expf(v[i] - m); s += e[i]; }
#pragma unroll
  for (int o = 32; o; o >>= 1) s += __shfl_xor(s, o);
  if (!lane) rs[wid] = s;
  __syncthreads();
  s = rs[0] + rs[1] + rs[2] + rs[3];
  const float inv = 1.0f / s;
  short8 wv;
#pragma unroll
  for (int i = 0; i < 8; ++i) wv[i] = f2bf(e[i] * inv);
  *reinterpret_cast<short8*>(P + row * 2048 + t * 8) = wv;
}

// layernorm of (p0 + p1 + bias + res), emitting f32 H and bf16 Hb.
__global__ __launch_bounds__(256)
void layernorm_fused(const float* __restrict__ p0, const float* __restrict__ p1,
                     const float* __restrict__ bias, const float* __restrict__ res,
                     const float* __restrict__ g, const float* __restrict__ bb,
                     float* __restrict__ H, ushort* __restrict__ Hb) {
  const long row = blockIdx.x;
  const long base = row * 2048;
  const int t = threadIdx.x, lane = t & 63, wid = t >> 6;
  const long i = base + t * 8;
  const int c0 = t * 8;
  float v[8];
  {
    float4 a0 = *(const float4*)(p0 + i),  a1 = *(const float4*)(p0 + i + 4);
    float4 q0 = *(const float4*)(p1 + i),  q1 = *(const float4*)(p1 + i + 4);
    float4 r0 = *(const float4*)(res + i), r1 = *(const float4*)(res + i + 4);
    float4 b0 = *(const float4*)(bias + c0), b1 = *(const float4*)(bias + c0 + 4);
    v[0] = a0.x + q0.x + r0.x + b0.x; v[1] = a0.y + q0.y + r0.y + b0.y;
    v[2] = a0.z + q0.z + r0.z + b0.z; v[3] = a0.w + q0.w + r0.w + b0.w;
    v[4] = a1.x + q1.x + r1.x + b1.x; v[5] = a1.y + q1.y + r1.y + b1.y;
    v[6] = a1.z + q1.z + r1.z + b1.z; v[7] = a1.w + q1.w + r1.w + b1.w;
  }
  float s = 0.f, ss = 0.f;
#pragma unroll
  for (int i2 = 0; i2 < 8; ++i2) { s += v[i2]; ss += v[i2] * v[i2]; }
#pragma unroll
  for (int o = 32; o; o >>= 1) { s += __shfl_xor(s, o); ss += __shfl_xor(ss, o); }
  __shared__ float r1s[4], r2s[4];
  if (!lane) { r1s[wid] = s; r2s[wid] = ss; }
  __syncthreads();
  s = r1s[0] + r1s[1] + r1s[2] + r1s[3];
  ss = r2s[0] + r2s[1] + r2s[2] + r2s[3];
  const float mu = s * (1.0f / 2048.0f);
  const float var = ss * (1.0f / 2048.0f) - mu * mu;
  const float inv = rsqrtf(var + 1e-5f);
  float o0[8];
  short8 wv;
#pragma unroll
  for (int i2 = 0; i2 < 8; ++i2) {
    const int c = c0 + i2;
    o0[i2] = (v[i2] - mu) * inv * g[c] + bb[c];
    wv[i2] = f2bf(o0[i2]);
  }
  float4 w0 = {o0[0], o0[1], o0[2], o0[3]}, w1 = {o0[4], o0[5], o0[6], o0[7]};
  *reinterpret_cast<float4*>(H + i) = w0;
  *reinterpret_cast<float4*>(H + i + 4) = w1;
  *reinterpret_cast<short8*>(Hb + i) = wv;
}

extern "C" void kernel_launch(void* const* d_in, const int* in_sizes, int n_in,
                              void* d_out, int out_size, void* d_ws, size_t ws_size,
                              hipStream_t stream) {
  const float* x    = (const float*)d_in[0];
  const float* wq   = (const float*)d_in[1];
  const float* bq   = (const float*)d_in[2];
  const float* wk   = (const float*)d_in[3];
  const float* bk   = (const float*)d_in[4];
  const float* wv   = (const float*)d_in[5];
  const float* bv   = (const float*)d_in[6];
  const float* wd   = (const float*)d_in[7];
  const float* bd   = (const float*)d_in[8];
  const float* ln_g = (const float*)d_in[9];
  const float* ln_b = (const float*)d_in[10];
  const float* w1   = (const float*)d_in[11];
  const float* b1   = (const float*)d_in[12];
  const float* w2   = (const float*)d_in[13];
  const float* b2   = (const float*)d_in[14];
  float* out = (float*)d_out;

  // ---- workspace layout (233 MiB, aliased) ----
  char* p = (char*)d_ws;
  const size_t MB = 1048576;
  ushort* wdb    = (ushort*)(p + 0 * MB);     // 8 MB   [dead after attn-out]
  ushort* w1b    = (ushort*)(p + 8 * MB);     // 32 MB  [dead after mlp1]
  ushort* w2b    = (ushort*)(p + 40 * MB);    // 32 MB  [live till mlp2]
  float*  bqkv   = (float*) (p + 72 * MB);    // 24 KB
  ushort* xb     = (ushort*)(p + 73 * MB);    // 16 MB  -> probs
  ushort* probs  = xb;
  ushort* qkv    = (ushort*)(p + 89 * MB);    // 48 MB  -> partA -> mlpb
  float*  partA  = (float*) (p + 89 * MB);    // 64 MB (z-stride 32 MB)
  ushort* mlpb   = (ushort*)(p + 89 * MB);    // 64 MB
  ushort* vT     = (ushort*)(p + 137 * MB);   // 16 MB  [dead after PV]
  ushort* wqkvb  = (ushort*)(p + 153 * MB);   // 24 MB  [dead after QKV]
  float*  scores = (float*) (p + 153 * MB);   // 32 MB  [dead after softmax]
  ushort* ctx    = (ushort*)(p + 153 * MB);   // 16 MB  [dead after attn-out]
  float*  partM0 = (float*) (p + 0 * MB);     // 32 MB  (wdb/w1b dead by mlp2)
  float*  partM1 = (float*) (p + 153 * MB);   // 32 MB
  float*  h      = (float*) (p + 185 * MB);   // 32 MB  [live till end]
  ushort* hb     = (ushort*)(p + 217 * MB);   // 16 MB  [dead after mlp1]

  const dim3 blk(256), blk512(512);
  const long SQ = (long)SEQ * SEQ;
  const size_t LDSB = 49152;

  // ---- bf16 conversions ----
  cvt8<<<4096, blk, 0, stream>>>(x, xb);
  cvt8<<<2048, blk, 0, stream>>>(wq, wqkvb);
  cvt8<<<2048, blk, 0, stream>>>(wk, wqkvb + 4194304);
  cvt8<<<2048, blk, 0, stream>>>(wv, wqkvb + 8388608);
  cvt8<<<2048, blk, 0, stream>>>(wd, wdb);
  cvt8<<<8192, blk, 0, stream>>>(w1, w1b);
  cvt8<<<8192, blk, 0, stream>>>(w2, w2b);
  concat3<<<24, blk, 0, stream>>>(bq, bk, bv, bqkv);

  // fused QKV: [4096,2048] x [6144,2048]^T -> qkv bf16 [4096][6144]
  gemm128<EPI_QKV><<<dim3(24, 32, 1), blk512, LDSB, stream>>>(
      xb, wqkvb, bqkv, qkv, 6144, 2048, 2048, 2048, 6144, 0, 0, 0, 1.f);

  transpose_v<<<dim3(64, 64, 2), blk, 0, stream>>>(qkv, vT);

  // scores = q k^T / sqrt(E), per batch (q,k strided inside qkv)
  gemm128<EPI_SCORES><<<dim3(8, 16, 2), blk512, LDSB, stream>>>(
      qkv, qkv + 2048, nullptr, scores, 2048, 2048, 6144, 6144, 2048,
      2048L * 6144, 2048L * 6144, SQ, 0.022097086912079608f);

  softmax_rows<<<dim3(4096), blk, 0, stream>>>(scores, probs);

  // ctx = probs @ v
  gemm128<EPI_PV><<<dim3(8, 16, 2), blk512, LDSB, stream>>>(
      probs, vT, nullptr, ctx, 2048, 2048, 2048, 2048, 2048,
      SQ, SQ, SQ, 1.f);

  // attn-out, split-K=2: partA[z] = ctx[:, z*1024:+1024] @ wd^T-slice
  gemm128<EPI_SCORES><<<dim3(8, 32, 2), blk512, LDSB, stream>>>(
      ctx, wdb, nullptr, partA, 2048, 1024, 2048, 2048, 2048,
      1024, 1024, 8388608, 1.f);

  // h = LN(partA0 + partA1 + bd + x); hb = bf16(h)
  layernorm_fused<<<4096, blk, 0, stream>>>(
      partA, partA + 8388608, bd, x, ln_g, ln_b, h, hb);

  // mlpb = gelu(h @ w1^T + b1)
  gemm128<EPI_GELU><<<dim3(32, 32, 1), blk512, LDSB, stream>>>(
      hb, w1b, b1, mlpb, 8192, 2048, 2048, 2048, 8192, 0, 0, 0, 1.f);

  // mlp2, split-K=2: partM[z] = mlpb[:, z*4096:+4096] @ w2^T-slice
  gemm128<EPI_SCORES><<<dim3(8, 32, 2), blk512, LDSB, stream>>>(
      mlpb, w2b, nullptr, partM0, 2048, 4096, 8192, 8192, 2048,
      4096, 4096, (long)(153 * MB / 4), 1.f);
  // out = partM0 + partM1 + b2 + h
  reduce2<<<4096, blk, 0, stream>>>(partM0, partM1, b2, h, out);
}

// Round 13
// 659.267 us; speedup vs baseline: 1.0735x; 1.0735x over previous
//
#include <hip/hip_runtime.h>
#include <math.h>

// PhiDecoderLayer on MI355X. B=2, S=2048, E=2048, MLP=8192, fp32 in/out.
// Round 13: r10 GEMM cores (best: 661us) with launch-graph re-plumbing:
//  - QKV split into QK (gemm256, 256 blocks = exactly 1 round) and a
//    direct V^T gemm (vT[e][s] = wv[e]·x[s] + bv[e], gemm_bt w/ row-bias),
//    eliminating the transpose_v kernel and the 1.5-round quantization.
//  - scores stored bf16 (softmax reads bf16) to halve that round-trip.

#define SEQ 2048
#define EMB 2048
#define MLPD 8192

typedef __attribute__((ext_vector_type(8))) short short8;
typedef __attribute__((ext_vector_type(4))) float floatx4;
typedef unsigned short ushort;

__device__ __forceinline__ short f2bf(float f) {
  union { float f; unsigned u; } v; v.f = f;
  unsigned r = v.u + 0x7FFFu + ((v.u >> 16) & 1u);
  return (short)(r >> 16);
}
__device__ __forceinline__ float bf2f(ushort u) {
  union { unsigned u; float f; } v; v.u = ((unsigned)u) << 16;
  return v.f;
}

// async global->LDS, 16B per lane. LDS dest = wave-uniform base + lane*16.
__device__ __forceinline__ void gload16(const ushort* g, ushort* l) {
  __builtin_amdgcn_global_load_lds(
      (__attribute__((address_space(1))) void*)g,
      (__attribute__((address_space(3))) void*)(unsigned)(unsigned long)l,
      16, 0, 0);
}

enum { EPI_QKV = 0, EPI_SCORES = 1, EPI_PV = 2, EPI_GELU = 4,
       EPI_VT = 5, EPI_SBF16 = 6 };

// ============================================================================
// 256x256 tile, BK=64, 8 waves — r10 structure (one barrier per phase).
// ============================================================================
template<int EPI>
__global__ __launch_bounds__(512, 2)
void gemm256(const ushort* __restrict__ A, const ushort* __restrict__ B,
             const float* __restrict__ bias, void* __restrict__ Cp,
             int N, int K, int lda, int ldb, int ldc,
             long sA, long sB, long sC, float scale)
{
  extern __shared__ ushort lds[];   // 65536 ushorts = 128 KiB
  const int t = threadIdx.x;
  const int lane = t & 63, w = t >> 6;
  const int wm = w >> 2, wn = w & 3;
  const long bm = (long)blockIdx.y * 256;
  const long bn = (long)blockIdx.x * 256;
  A += (long)blockIdx.z * sA;
  B += (long)blockIdx.z * sB;

  const int srow = (w << 3) + (lane >> 3);
  const int gcol = (lane & 7) ^ ((lane >> 3) & 7);
  const ushort* Ab = A + (bm + srow) * (long)lda + gcol * 8;
  const ushort* Bb = B + (bn + srow) * (long)ldb + gcol * 8;
  ushort* lw = lds + (w << 9);

#define STG_A0(LOFF, KK) do { gload16(Ab + (KK), lw + (LOFF)); \
    gload16(Ab + 64L * lda + (KK), lw + (LOFF) + 4096); } while (0)
#define STG_A1(LOFF, KK) do { gload16(Ab + 128L * lda + (KK), lw + (LOFF)); \
    gload16(Ab + 192L * lda + (KK), lw + (LOFF) + 4096); } while (0)
#define STG_B0(LOFF, KK) do { gload16(Bb + (KK), lw + (LOFF)); \
    gload16(Bb + 64L * ldb + (KK), lw + (LOFF) + 4096); } while (0)
#define STG_B1(LOFF, KK) do { gload16(Bb + 128L * ldb + (KK), lw + (LOFF)); \
    gload16(Bb + 192L * ldb + (KK), lw + (LOFF) + 4096); } while (0)

  const int l15 = lane & 15, q = lane >> 4, swz = l15 & 7;
  const int kx0 = (q ^ swz) << 3;
  const int kx1 = ((4 + q) ^ swz) << 3;
  const int arow = (wm << 13) + l15 * 64;
  const int brow = 16384 + ((wn >> 1) << 13) + ((wn & 1) << 12) + l15 * 64;

  floatx4 acc[8][4];
#pragma unroll
  for (int m = 0; m < 8; ++m)
#pragma unroll
    for (int n = 0; n < 4; ++n) acc[m][n] = (floatx4)0.0f;

  short8 A0[4], A1[4], B0[4], B1[4];

#define LDS8(IDX) (*(const short8*)&lds[IDX])
#define RD_ALK0(CB) do { _Pragma("unroll") for (int mf = 0; mf < 4; ++mf) \
    A0[mf] = LDS8((CB) + arow + mf * 1024 + kx0); } while (0)
#define RD_ALK1(CB) do { _Pragma("unroll") for (int mf = 0; mf < 4; ++mf) \
    A1[mf] = LDS8((CB) + arow + mf * 1024 + kx1); } while (0)
#define RD_AHK0(CB) do { _Pragma("unroll") for (int mf = 0; mf < 4; ++mf) \
    A0[mf] = LDS8((CB) + arow + (4 + mf) * 1024 + kx0); } while (0)
#define RD_AHK1(CB) do { _Pragma("unroll") for (int mf = 0; mf < 4; ++mf) \
    A1[mf] = LDS8((CB) + arow + (4 + mf) * 1024 + kx1); } while (0)
#define RD_BK0(CB) do { _Pragma("unroll") for (int nf = 0; nf < 4; ++nf) \
    B0[nf] = LDS8((CB) + brow + nf * 1024 + kx0); } while (0)
#define RD_BK1(CB) do { _Pragma("unroll") for (int nf = 0; nf < 4; ++nf) \
    B1[nf] = LDS8((CB) + brow + nf * 1024 + kx1); } while (0)

#define MMA16(MO, AX, BX) do {                                            \
    __builtin_amdgcn_s_setprio(1);                                        \
    _Pragma("unroll") for (int mf = 0; mf < 4; ++mf)                      \
      _Pragma("unroll") for (int nf = 0; nf < 4; ++nf)                    \
        acc[(MO)+mf][nf] = __builtin_amdgcn_mfma_f32_16x16x32_bf16(       \
            AX[mf], BX[nf], acc[(MO)+mf][nf], 0, 0, 0);                   \
    __builtin_amdgcn_s_setprio(0);                                        \
  } while (0)

#define BARR() __builtin_amdgcn_s_barrier()
#define VMC4  asm volatile("s_waitcnt vmcnt(4)" ::: "memory")

#define KTILE(CB, NB, K1, K2) do {                                        \
    RD_ALK0(CB); RD_BK0(CB); STG_A0((NB) + 0, K1);                        \
    MMA16(0, A0, B0); BARR();                                             \
    RD_ALK1(CB); RD_BK1(CB); STG_A1((NB) + 8192, K1);                     \
    MMA16(0, A1, B1); BARR();                                             \
    RD_AHK0(CB); STG_B0((CB) + 16384, K2);                                \
    MMA16(4, A0, B0); BARR();                                             \
    RD_AHK1(CB); STG_B1((CB) + 24576, K2);                                \
    MMA16(4, A1, B1); VMC4; BARR();                                       \
  } while (0)

  STG_A0(0, 0);              STG_A1(8192, 0);
  STG_B0(16384, 0);          STG_B1(24576, 0);
  {
    const int k1p = (K > 64) ? 64 : 0;
    STG_B0(32768 + 16384, k1p);
    STG_B1(32768 + 24576, k1p);
  }
  asm volatile("s_waitcnt vmcnt(4)" ::: "memory");
  BARR();

  const int NT = K >> 6;
  for (int kt = 0; kt < NT; kt += 2) {
    const int k1 = ((kt + 1 < NT) ? kt + 1 : NT - 1) << 6;
    const int k2 = ((kt + 2 < NT) ? kt + 2 : NT - 1) << 6;
    const int k3 = ((kt + 3 < NT) ? kt + 3 : NT - 1) << 6;
    KTILE(0,     32768, k1, k2);
    KTILE(32768, 0,     k2, k3);
  }
  asm volatile("s_waitcnt vmcnt(0)" ::: "memory");
#undef KTILE
#undef MMA16
#undef RD_ALK0
#undef RD_ALK1
#undef RD_AHK0
#undef RD_AHK1
#undef RD_BK0
#undef RD_BK1
#undef LDS8
#undef STG_A0
#undef STG_A1
#undef STG_B0
#undef STG_B1

  const int lq = lane >> 4;
#pragma unroll
  for (int mf = 0; mf < 8; ++mf) {
#pragma unroll
    for (int nf = 0; nf < 4; ++nf) {
#pragma unroll
      for (int i = 0; i < 4; ++i) {
        const long r = bm + wm * 128 + mf * 16 + lq * 4 + i;
        const long c = bn + wn * 64 + nf * 16 + l15;
        float val = acc[mf][nf][i];
        if constexpr (EPI == EPI_QKV) {
          val += bias[c];
          ((ushort*)Cp)[r * (long)ldc + c] = (ushort)f2bf(val);
        } else if constexpr (EPI == EPI_SCORES) {  // raw f32 partial
          ((float*)Cp)[(long)blockIdx.z * sC + r * (long)ldc + c] = val * scale;
        } else {  // EPI_GELU exact
          val += bias[c];
          float g = 0.5f * val * (1.0f + erff(val * 0.70710678118f));
          ((ushort*)Cp)[r * (long)ldc + c] = (ushort)f2bf(g);
        }
      }
    }
  }
}

// ============================================================================
// 128x128 m97-structure kernel — scores (bf16 out), PV, and direct-V^T.
// ============================================================================
template<int EPI>
__global__ __launch_bounds__(256)
void gemm_bt(const ushort* __restrict__ A, const ushort* __restrict__ B,
             const float* __restrict__ bias, void* __restrict__ Cp,
             int N, int K, int lda, int ldb, int ldc,
             long sA, long sB, long sC, float scale)
{
  __shared__ ushort As[128 * 32];
  __shared__ ushort Bs[128 * 32];

  const int t = threadIdx.x;
  const int lane = t & 63, wid = t >> 6;
  const int wm = wid >> 1, wn = wid & 1;
  const long bm = (long)blockIdx.y * 128;
  const long bn = (long)blockIdx.x * 128;
  A += (long)blockIdx.z * sA;
  B += (long)blockIdx.z * sB;

  const int srow = (wid << 5) + (lane >> 2);
  const int scol = (lane & 3) << 3;
  const ushort* a0 = A + (bm + srow) * (long)lda + scol;
  const ushort* a1 = a0 + 16L * lda;
  const ushort* b0 = B + (bn + srow) * (long)ldb + scol;
  const ushort* b1 = b0 + 16L * ldb;
  ushort* lA0 = As + (wid << 10);
  ushort* lA1 = lA0 + 512;
  ushort* lB0 = Bs + (wid << 10);
  ushort* lB1 = lB0 + 512;

  floatx4 acc[4][4];
#pragma unroll
  for (int m = 0; m < 4; ++m)
#pragma unroll
    for (int n = 0; n < 4; ++n) acc[m][n] = (floatx4)0.0f;

  const int l15 = lane & 15, kq = (lane >> 4) << 3;
  const int abase = ((wm << 6) + l15) * 32 + kq;
  const int bbase = ((wn << 6) + l15) * 32 + kq;

  for (int kb = 0; kb < K; kb += 32) {
    gload16(a0 + kb, lA0);
    gload16(a1 + kb, lA1);
    gload16(b0 + kb, lB0);
    gload16(b1 + kb, lB1);
    __syncthreads();

    short8 a[4], b[4];
#pragma unroll
    for (int m = 0; m < 4; ++m)
      a[m] = *reinterpret_cast<const short8*>(&As[abase + m * (16 * 32)]);
#pragma unroll
    for (int n = 0; n < 4; ++n)
      b[n] = *reinterpret_cast<const short8*>(&Bs[bbase + n * (16 * 32)]);
#pragma unroll
    for (int m = 0; m < 4; ++m)
#pragma unroll
      for (int n = 0; n < 4; ++n)
        acc[m][n] = __builtin_amdgcn_mfma_f32_16x16x32_bf16(a[m], b[n], acc[m][n], 0, 0, 0);
    __syncthreads();
  }

  const int lq = lane >> 4;
#pragma unroll
  for (int m = 0; m < 4; ++m) {
#pragma unroll
    for (int n = 0; n < 4; ++n) {
#pragma unroll
      for (int i = 0; i < 4; ++i) {
        const long r = bm + wm * 64 + m * 16 + lq * 4 + i;
        const long c = bn + wn * 64 + n * 16 + l15;
        float val = acc[m][n][i];
        if constexpr (EPI == EPI_SBF16) {        // scores, scaled bf16
          ((ushort*)Cp)[(long)blockIdx.z * sC + r * (long)ldc + c] =
              (ushort)f2bf(val * scale);
        } else if constexpr (EPI == EPI_PV) {
          ((ushort*)Cp)[(long)blockIdx.z * sC + r * (long)ldc + c] = (ushort)f2bf(val);
        } else if constexpr (EPI == EPI_VT) {    // vT: row-bias (bv[e])
          val += bias[r];
          ((ushort*)Cp)[(long)blockIdx.z * sC + r * (long)ldc + c] = (ushort)f2bf(val);
        }
      }
    }
  }
}

// out = p0 + p1 + bias + res  (f32, 8 elems/thread, N=2048 columns)
__global__ __launch_bounds__(256)
void reduce2(const float* __restrict__ p0, const float* __restrict__ p1,
             const float* __restrict__ bias, const float* __restrict__ res,
             float* __restrict__ out)
{
  const long i = ((long)blockIdx.x * 256 + threadIdx.x) * 8;
  const int c = (int)(i & 2047);
  float4 a0 = *(const float4*)(p0 + i),  a1 = *(const float4*)(p0 + i + 4);
  float4 q0 = *(const float4*)(p1 + i),  q1 = *(const float4*)(p1 + i + 4);
  float4 r0 = *(const float4*)(res + i), r1 = *(const float4*)(res + i + 4);
  float4 b0 = *(const float4*)(bias + c), b1 = *(const float4*)(bias + c + 4);
  float4 o0 = {a0.x + q0.x + r0.x + b0.x, a0.y + q0.y + r0.y + b0.y,
               a0.z + q0.z + r0.z + b0.z, a0.w + q0.w + r0.w + b0.w};
  float4 o1 = {a1.x + q1.x + r1.x + b1.x, a1.y + q1.y + r1.y + b1.y,
               a1.z + q1.z + r1.z + b1.z, a1.w + q1.w + r1.w + b1.w};
  *(float4*)(out + i) = o0;
  *(float4*)(out + i + 4) = o1;
}

__global__ __launch_bounds__(256)
void cvt8(const float* __restrict__ s, ushort* __restrict__ d) {
  const long i = ((long)blockIdx.x * 256 + threadIdx.x) * 8;
  float4 a = *reinterpret_cast<const float4*>(s + i);
  float4 b = *reinterpret_cast<const float4*>(s + i + 4);
  short8 v;
  v[0] = f2bf(a.x); v[1] = f2bf(a.y); v[2] = f2bf(a.z); v[3] = f2bf(a.w);
  v[4] = f2bf(b.x); v[5] = f2bf(b.y); v[6] = f2bf(b.z); v[7] = f2bf(b.w);
  *reinterpret_cast<short8*>(d + i) = v;
}

__global__ __launch_bounds__(256)
void concat2(const float* __restrict__ b0, const float* __restrict__ b1,
             float* __restrict__ dst) {
  const int i = blockIdx.x * 256 + threadIdx.x;  // 4096 total
  dst[i] = (i < 2048) ? b0[i] : b1[i - 2048];
}

// row softmax over bf16 scores: [4096][2048] bf16 -> probs bf16
__global__ __launch_bounds__(256)
void softmax_rows(const ushort* __restrict__ S, ushort* __restrict__ P) {
  const long row = blockIdx.x;
  const ushort* src = S + row * 2048;
  const int t = threadIdx.x, lane = t & 63, wid = t >> 6;
  short8 raw = *reinterpret_cast<const short8*>(src + t * 8);
  float v[8];
#pragma unroll
  for (int i = 0; i < 8; ++i) v[i] = bf2f((ushort)raw[i]);
  float m = v[0];
#pragma unroll
  for (int i = 1; i < 8; ++i) m = fmaxf(m, v[i]);
#pragma unroll
  for (int o = 32; o; o >>= 1) m = fmaxf(m, __shfl_xor(m, o));
  __shared__ float rm[4], rs[4];
  if (!lane) rm[wid] = m;
  __syncthreads();
  m = fmaxf(fmaxf(rm[0], rm[1]), fmaxf(rm[2], rm[3]));
  float e[8], s = 0.f;
#pragma unroll
  for (int i = 0; i < 8; ++i) { e[i] = __expf(v[i] - m); s += e[i]; }
#pragma unroll
  for (int o = 32; o; o >>= 1) s += __shfl_xor(s, o);
  if (!lane) rs[wid] = s;
  __syncthreads();
  s = rs[0] + rs[1] + rs[2] + rs[3];
  const float inv = 1.0f / s;
  short8 wv;
#pragma unroll
  for (int i = 0; i < 8; ++i) wv[i] = f2bf(e[i] * inv);
  *reinterpret_cast<short8*>(P + row * 2048 + t * 8) = wv;
}

// layernorm of (p0 + p1 + bias + res), emitting f32 H and bf16 Hb.
__global__ __launch_bounds__(256)
void layernorm_fused(const float* __restrict__ p0, const float* __restrict__ p1,
                     const float* __restrict__ bias, const float* __restrict__ res,
                     const float* __restrict__ g, const float* __restrict__ bb,
                     float* __restrict__ H, ushort* __restrict__ Hb) {
  const long row = blockIdx.x;
  const long base = row * 2048;
  const int t = threadIdx.x, lane = t & 63, wid = t >> 6;
  const long i = base + t * 8;
  const int c0 = t * 8;
  float v[8];
  {
    float4 a0 = *(const float4*)(p0 + i),  a1 = *(const float4*)(p0 + i + 4);
    float4 q0 = *(const float4*)(p1 + i),  q1 = *(const float4*)(p1 + i + 4);
    float4 r0 = *(const float4*)(res + i), r1 = *(const float4*)(res + i + 4);
    float4 b0 = *(const float4*)(bias + c0), b1 = *(const float4*)(bias + c0 + 4);
    v[0] = a0.x + q0.x + r0.x + b0.x; v[1] = a0.y + q0.y + r0.y + b0.y;
    v[2] = a0.z + q0.z + r0.z + b0.z; v[3] = a0.w + q0.w + r0.w + b0.w;
    v[4] = a1.x + q1.x + r1.x + b1.x; v[5] = a1.y + q1.y + r1.y + b1.y;
    v[6] = a1.z + q1.z + r1.z + b1.z; v[7] = a1.w + q1.w + r1.w + b1.w;
  }
  float s = 0.f, ss = 0.f;
#pragma unroll
  for (int i2 = 0; i2 < 8; ++i2) { s += v[i2]; ss += v[i2] * v[i2]; }
#pragma unroll
  for (int o = 32; o; o >>= 1) { s += __shfl_xor(s, o); ss += __shfl_xor(ss, o); }
  __shared__ float r1s[4], r2s[4];
  if (!lane) { r1s[wid] = s; r2s[wid] = ss; }
  __syncthreads();
  s = r1s[0] + r1s[1] + r1s[2] + r1s[3];
  ss = r2s[0] + r2s[1] + r2s[2] + r2s[3];
  const float mu = s * (1.0f / 2048.0f);
  const float var = ss * (1.0f / 2048.0f) - mu * mu;
  const float inv = rsqrtf(var + 1e-5f);
  float o0[8];
  short8 wv;
#pragma unroll
  for (int i2 = 0; i2 < 8; ++i2) {
    const int c = c0 + i2;
    o0[i2] = (v[i2] - mu) * inv * g[c] + bb[c];
    wv[i2] = f2bf(o0[i2]);
  }
  float4 w0 = {o0[0], o0[1], o0[2], o0[3]}, w1 = {o0[4], o0[5], o0[6], o0[7]};
  *reinterpret_cast<float4*>(H + i) = w0;
  *reinterpret_cast<float4*>(H + i + 4) = w1;
  *reinterpret_cast<short8*>(Hb + i) = wv;
}

extern "C" void kernel_launch(void* const* d_in, const int* in_sizes, int n_in,
                              void* d_out, int out_size, void* d_ws, size_t ws_size,
                              hipStream_t stream) {
  const float* x    = (const float*)d_in[0];
  const float* wq   = (const float*)d_in[1];
  const float* bq   = (const float*)d_in[2];
  const float* wk   = (const float*)d_in[3];
  const float* bk   = (const float*)d_in[4];
  const float* wv   = (const float*)d_in[5];
  const float* bv   = (const float*)d_in[6];
  const float* wd   = (const float*)d_in[7];
  const float* bd   = (const float*)d_in[8];
  const float* ln_g = (const float*)d_in[9];
  const float* ln_b = (const float*)d_in[10];
  const float* w1   = (const float*)d_in[11];
  const float* b1   = (const float*)d_in[12];
  const float* w2   = (const float*)d_in[13];
  const float* b2   = (const float*)d_in[14];
  float* out = (float*)d_out;

  (void)hipFuncSetAttribute((const void*)&gemm256<EPI_QKV>,
      hipFuncAttributeMaxDynamicSharedMemorySize, 131072);
  (void)hipFuncSetAttribute((const void*)&gemm256<EPI_GELU>,
      hipFuncAttributeMaxDynamicSharedMemorySize, 131072);
  (void)hipFuncSetAttribute((const void*)&gemm256<EPI_SCORES>,
      hipFuncAttributeMaxDynamicSharedMemorySize, 131072);

  // ---- workspace layout (233 MiB, aliased; liveness audited) ----
  char* p = (char*)d_ws;
  const size_t MB = 1048576;
  ushort* wdb    = (ushort*)(p + 0 * MB);     // 8 MB   [dead after attn-out]
  ushort* w1b    = (ushort*)(p + 8 * MB);     // 32 MB  [dead after mlp1]
  ushort* w2b    = (ushort*)(p + 40 * MB);    // 32 MB  [live till mlp2]
  float*  bqk    = (float*) (p + 72 * MB);    // 16 KB
  ushort* xb     = (ushort*)(p + 73 * MB);    // 16 MB  [dead after vT] -> probs
  ushort* probs  = xb;
  ushort* qk     = (ushort*)(p + 89 * MB);    // 32 MB  [dead after scores]
  ushort* wqkb   = (ushort*)(p + 121 * MB);   // 16 MB  [dead after QK]
  ushort* vT     = (ushort*)(p + 121 * MB);   // 16 MB  [dead after PV]
  ushort* wvb    = (ushort*)(p + 137 * MB);   // 8 MB   [dead after vT]
  ushort* scoresb= (ushort*)(p + 137 * MB);   // 16 MB  [dead after softmax]
  float*  partA  = (float*) (p + 89 * MB);    // 64 MB (89-153) attn-out out
  ushort* mlpb   = (ushort*)(p + 89 * MB);    // 64 MB  mlp1 out
  float*  h      = (float*) (p + 153 * MB);   // 32 MB  [live till end]
  ushort* hb     = (ushort*)(p + 185 * MB);   // 16 MB  [dead after mlp1]
  ushort* ctx    = (ushort*)(p + 201 * MB);   // 16 MB  [dead after attn-out]
  float*  partM0 = (float*) (p + 0 * MB);     // 32 MB  (wdb/w1b dead)
  float*  partM1 = (float*) (p + 201 * MB);   // 32 MB  (ctx dead)

  const dim3 blk(256), blk512(512);
  const long SQ = (long)SEQ * SEQ;

  // ---- bf16 conversions ----
  cvt8<<<4096, blk, 0, stream>>>(x, xb);
  cvt8<<<2048, blk, 0, stream>>>(wq, wqkb);
  cvt8<<<2048, blk, 0, stream>>>(wk, wqkb + 4194304);
  cvt8<<<2048, blk, 0, stream>>>(wv, wvb);
  cvt8<<<2048, blk, 0, stream>>>(wd, wdb);
  cvt8<<<8192, blk, 0, stream>>>(w1, w1b);
  cvt8<<<8192, blk, 0, stream>>>(w2, w2b);
  concat2<<<16, blk, 0, stream>>>(bq, bk, bqk);

  // QK: [4096,2048] x [4096,2048]^T -> qk bf16 [4096][4096] (1 full round)
  gemm256<EPI_QKV><<<dim3(16, 16, 1), blk512, 131072, stream>>>(
      xb, wqkb, bqk, qk, 4096, 2048, 2048, 2048, 4096, 0, 0, 0, 1.f);

  // vT[b][e][s] = wv[e]·x[b,s] + bv[e]  (direct transposed V)
  gemm_bt<EPI_VT><<<dim3(16, 16, 2), blk, 0, stream>>>(
      wvb, xb, bv, vT, 2048, 2048, 2048, 2048, 2048,
      0, SQ, SQ, 1.f);

  // scores = q k^T / sqrt(E) per batch -> bf16
  gemm_bt<EPI_SBF16><<<dim3(16, 16, 2), blk, 0, stream>>>(
      qk, qk + 2048, nullptr, scoresb, 2048, 2048, 4096, 4096, 2048,
      2048L * 4096, 2048L * 4096, SQ, 0.022097086912079608f);

  softmax_rows<<<dim3(4096), blk, 0, stream>>>(scoresb, probs);

  // ctx = probs @ v
  gemm_bt<EPI_PV><<<dim3(16, 16, 2), blk, 0, stream>>>(
      probs, vT, nullptr, ctx, 2048, 2048, 2048, 2048, 2048,
      SQ, SQ, SQ, 1.f);

  // attn-out, split-K=2: partA[z] = ctx[:, z*1024:+1024] @ wd^T-slice
  gemm256<EPI_SCORES><<<dim3(8, 16, 2), blk512, 131072, stream>>>(
      ctx, wdb, nullptr, partA, 2048, 1024, 2048, 2048, 2048,
      1024, 1024, 8388608, 1.f);

  // h = LN(partA0 + partA1 + bd + x); hb = bf16(h)
  layernorm_fused<<<4096, blk, 0, stream>>>(
      partA, partA + 8388608, bd, x, ln_g, ln_b, h, hb);

  // mlpb = gelu(h @ w1^T + b1)
  gemm256<EPI_GELU><<<dim3(32, 16, 1), blk512, 131072, stream>>>(
      hb, w1b, b1, mlpb, 8192, 2048, 2048, 2048, 8192, 0, 0, 0, 1.f);

  // mlp2, split-K=2: partM[z] = mlpb[:, z*4096:+4096] @ w2^T-slice
  gemm256<EPI_SCORES><<<dim3(8, 16, 2), blk512, 131072, stream>>>(
      mlpb, w2b, nullptr, partM0, 2048, 4096, 8192, 8192, 2048,
      4096, 4096, (long)(201 * MB / 4), 1.f);
  // out = partM0 + partM1 + b2 + h
  reduce2<<<4096, blk, 0, stream>>>(partM0, partM1, b2, h, out);
}

// Round 14
// 625.845 us; speedup vs baseline: 1.1308x; 1.0534x over previous
//
#include <hip/hip_runtime.h>
#include <math.h>

// PhiDecoderLayer on MI355X. B=2, S=2048, E=2048, MLP=8192, fp32 in/out.
// Round 14: r13 + gemm_bt upgraded to BK=64 with gemm256's proven granule-XOR
// swizzle (its 128x64 tiles are exactly gemm256's half-tile shape) -> kills
// the ~1.7e7 LDS bank conflicts and halves barrier count. Same single-buffer
// stage->sync->compute->sync skeleton. gemm256 (r10) untouched.

#define SEQ 2048
#define EMB 2048
#define MLPD 8192

typedef __attribute__((ext_vector_type(8))) short short8;
typedef __attribute__((ext_vector_type(4))) float floatx4;
typedef unsigned short ushort;

__device__ __forceinline__ short f2bf(float f) {
  union { float f; unsigned u; } v; v.f = f;
  unsigned r = v.u + 0x7FFFu + ((v.u >> 16) & 1u);
  return (short)(r >> 16);
}
__device__ __forceinline__ float bf2f(ushort u) {
  union { unsigned u; float f; } v; v.u = ((unsigned)u) << 16;
  return v.f;
}

// async global->LDS, 16B per lane. LDS dest = wave-uniform base + lane*16.
__device__ __forceinline__ void gload16(const ushort* g, ushort* l) {
  __builtin_amdgcn_global_load_lds(
      (__attribute__((address_space(1))) void*)g,
      (__attribute__((address_space(3))) void*)(unsigned)(unsigned long)l,
      16, 0, 0);
}

enum { EPI_QKV = 0, EPI_SCORES = 1, EPI_PV = 2, EPI_GELU = 4,
       EPI_VT = 5, EPI_SBF16 = 6 };

// ============================================================================
// 256x256 tile, BK=64, 8 waves — r10 structure (one barrier per phase).
// ============================================================================
template<int EPI>
__global__ __launch_bounds__(512, 2)
void gemm256(const ushort* __restrict__ A, const ushort* __restrict__ B,
             const float* __restrict__ bias, void* __restrict__ Cp,
             int N, int K, int lda, int ldb, int ldc,
             long sA, long sB, long sC, float scale)
{
  extern __shared__ ushort lds[];   // 65536 ushorts = 128 KiB
  const int t = threadIdx.x;
  const int lane = t & 63, w = t >> 6;
  const int wm = w >> 2, wn = w & 3;
  const long bm = (long)blockIdx.y * 256;
  const long bn = (long)blockIdx.x * 256;
  A += (long)blockIdx.z * sA;
  B += (long)blockIdx.z * sB;

  const int srow = (w << 3) + (lane >> 3);
  const int gcol = (lane & 7) ^ ((lane >> 3) & 7);
  const ushort* Ab = A + (bm + srow) * (long)lda + gcol * 8;
  const ushort* Bb = B + (bn + srow) * (long)ldb + gcol * 8;
  ushort* lw = lds + (w << 9);

#define STG_A0(LOFF, KK) do { gload16(Ab + (KK), lw + (LOFF)); \
    gload16(Ab + 64L * lda + (KK), lw + (LOFF) + 4096); } while (0)
#define STG_A1(LOFF, KK) do { gload16(Ab + 128L * lda + (KK), lw + (LOFF)); \
    gload16(Ab + 192L * lda + (KK), lw + (LOFF) + 4096); } while (0)
#define STG_B0(LOFF, KK) do { gload16(Bb + (KK), lw + (LOFF)); \
    gload16(Bb + 64L * ldb + (KK), lw + (LOFF) + 4096); } while (0)
#define STG_B1(LOFF, KK) do { gload16(Bb + 128L * ldb + (KK), lw + (LOFF)); \
    gload16(Bb + 192L * ldb + (KK), lw + (LOFF) + 4096); } while (0)

  const int l15 = lane & 15, q = lane >> 4, swz = l15 & 7;
  const int kx0 = (q ^ swz) << 3;
  const int kx1 = ((4 + q) ^ swz) << 3;
  const int arow = (wm << 13) + l15 * 64;
  const int brow = 16384 + ((wn >> 1) << 13) + ((wn & 1) << 12) + l15 * 64;

  floatx4 acc[8][4];
#pragma unroll
  for (int m = 0; m < 8; ++m)
#pragma unroll
    for (int n = 0; n < 4; ++n) acc[m][n] = (floatx4)0.0f;

  short8 A0[4], A1[4], B0[4], B1[4];

#define LDS8(IDX) (*(const short8*)&lds[IDX])
#define RD_ALK0(CB) do { _Pragma("unroll") for (int mf = 0; mf < 4; ++mf) \
    A0[mf] = LDS8((CB) + arow + mf * 1024 + kx0); } while (0)
#define RD_ALK1(CB) do { _Pragma("unroll") for (int mf = 0; mf < 4; ++mf) \
    A1[mf] = LDS8((CB) + arow + mf * 1024 + kx1); } while (0)
#define RD_AHK0(CB) do { _Pragma("unroll") for (int mf = 0; mf < 4; ++mf) \
    A0[mf] = LDS8((CB) + arow + (4 + mf) * 1024 + kx0); } while (0)
#define RD_AHK1(CB) do { _Pragma("unroll") for (int mf = 0; mf < 4; ++mf) \
    A1[mf] = LDS8((CB) + arow + (4 + mf) * 1024 + kx1); } while (0)
#define RD_BK0(CB) do { _Pragma("unroll") for (int nf = 0; nf < 4; ++nf) \
    B0[nf] = LDS8((CB) + brow + nf * 1024 + kx0); } while (0)
#define RD_BK1(CB) do { _Pragma("unroll") for (int nf = 0; nf < 4; ++nf) \
    B1[nf] = LDS8((CB) + brow + nf * 1024 + kx1); } while (0)

#define MMA16(MO, AX, BX) do {                                            \
    __builtin_amdgcn_s_setprio(1);                                        \
    _Pragma("unroll") for (int mf = 0; mf < 4; ++mf)                      \
      _Pragma("unroll") for (int nf = 0; nf < 4; ++nf)                    \
        acc[(MO)+mf][nf] = __builtin_amdgcn_mfma_f32_16x16x32_bf16(       \
            AX[mf], BX[nf], acc[(MO)+mf][nf], 0, 0, 0);                   \
    __builtin_amdgcn_s_setprio(0);                                        \
  } while (0)

#define BARR() __builtin_amdgcn_s_barrier()
#define VMC4  asm volatile("s_waitcnt vmcnt(4)" ::: "memory")

#define KTILE(CB, NB, K1, K2) do {                                        \
    RD_ALK0(CB); RD_BK0(CB); STG_A0((NB) + 0, K1);                        \
    MMA16(0, A0, B0); BARR();                                             \
    RD_ALK1(CB); RD_BK1(CB); STG_A1((NB) + 8192, K1);                     \
    MMA16(0, A1, B1); BARR();                                             \
    RD_AHK0(CB); STG_B0((CB) + 16384, K2);                                \
    MMA16(4, A0, B0); BARR();                                             \
    RD_AHK1(CB); STG_B1((CB) + 24576, K2);                                \
    MMA16(4, A1, B1); VMC4; BARR();                                       \
  } while (0)

  STG_A0(0, 0);              STG_A1(8192, 0);
  STG_B0(16384, 0);          STG_B1(24576, 0);
  {
    const int k1p = (K > 64) ? 64 : 0;
    STG_B0(32768 + 16384, k1p);
    STG_B1(32768 + 24576, k1p);
  }
  asm volatile("s_waitcnt vmcnt(4)" ::: "memory");
  BARR();

  const int NT = K >> 6;
  for (int kt = 0; kt < NT; kt += 2) {
    const int k1 = ((kt + 1 < NT) ? kt + 1 : NT - 1) << 6;
    const int k2 = ((kt + 2 < NT) ? kt + 2 : NT - 1) << 6;
    const int k3 = ((kt + 3 < NT) ? kt + 3 : NT - 1) << 6;
    KTILE(0,     32768, k1, k2);
    KTILE(32768, 0,     k2, k3);
  }
  asm volatile("s_waitcnt vmcnt(0)" ::: "memory");
#undef KTILE
#undef MMA16
#undef RD_ALK0
#undef RD_ALK1
#undef RD_AHK0
#undef RD_AHK1
#undef RD_BK0
#undef RD_BK1
#undef LDS8
#undef STG_A0
#undef STG_A1
#undef STG_B0
#undef STG_B1

  const int lq = lane >> 4;
#pragma unroll
  for (int mf = 0; mf < 8; ++mf) {
#pragma unroll
    for (int nf = 0; nf < 4; ++nf) {
#pragma unroll
      for (int i = 0; i < 4; ++i) {
        const long r = bm + wm * 128 + mf * 16 + lq * 4 + i;
        const long c = bn + wn * 64 + nf * 16 + l15;
        float val = acc[mf][nf][i];
        if constexpr (EPI == EPI_QKV) {
          val += bias[c];
          ((ushort*)Cp)[r * (long)ldc + c] = (ushort)f2bf(val);
        } else if constexpr (EPI == EPI_SCORES) {  // raw f32 partial
          ((float*)Cp)[(long)blockIdx.z * sC + r * (long)ldc + c] = val * scale;
        } else {  // EPI_GELU exact
          val += bias[c];
          float g = 0.5f * val * (1.0f + erff(val * 0.70710678118f));
          ((ushort*)Cp)[r * (long)ldc + c] = (ushort)f2bf(g);
        }
      }
    }
  }
}

// ============================================================================
// 128x128 tile, BK=64, 4 waves (2Mx2N), single-buffered, swizzled LDS
// (gemm256's half-tile layout: 128 rows x 64 cols, granule-XOR g^(row&7)).
// Used for scores (bf16 out), PV, and direct-V^T.
// ============================================================================
template<int EPI>
__global__ __launch_bounds__(256)
void gemm_bt(const ushort* __restrict__ A, const ushort* __restrict__ B,
             const float* __restrict__ bias, void* __restrict__ Cp,
             int N, int K, int lda, int ldb, int ldc,
             long sA, long sB, long sC, float scale)
{
  __shared__ ushort As[128 * 64];   // 16 KiB
  __shared__ ushort Bs[128 * 64];   // 16 KiB

  const int t = threadIdx.x;
  const int lane = t & 63, wid = t >> 6;
  const int wm = wid >> 1, wn = wid & 1;
  const long bm = (long)blockIdx.y * 128;
  const long bn = (long)blockIdx.x * 128;
  A += (long)blockIdx.z * sA;
  B += (long)blockIdx.z * sB;

  // staging: per gload, wave covers 8 rows x 8 granules (swizzled source);
  // 4 waves -> 32 rows per issue; 4 issues cover 128 rows.
  const int srow = (wid << 3) + (lane >> 3);            // 0..31
  const int gcol = (lane & 7) ^ ((lane >> 3) & 7);      // pre-swizzled granule
  const ushort* a0 = A + (bm + srow) * (long)lda + gcol * 8;
  const ushort* b0 = B + (bn + srow) * (long)ldb + gcol * 8;
  ushort* lA = As + (wid << 9);   // wid*512 = 8 rows of 64
  ushort* lB = Bs + (wid << 9);

  floatx4 acc[4][4];
#pragma unroll
  for (int m = 0; m < 4; ++m)
#pragma unroll
    for (int n = 0; n < 4; ++n) acc[m][n] = (floatx4)0.0f;

  // read geometry (swizzled): row*64 + ((q^swz) or (4+q)^swz)*8
  const int l15 = lane & 15, q = lane >> 4, swz = l15 & 7;
  const int kx0 = (q ^ swz) << 3;
  const int kx1 = ((4 + q) ^ swz) << 3;
  const int abase = ((wm << 6) + l15) * 64;
  const int bbase = ((wn << 6) + l15) * 64;

  for (int kb = 0; kb < K; kb += 64) {
#pragma unroll
    for (int i = 0; i < 4; ++i) {
      gload16(a0 + (32L * i) * lda + kb, lA + i * 2048);
      gload16(b0 + (32L * i) * ldb + kb, lB + i * 2048);
    }
    __syncthreads();

    short8 a0r[4], a1r[4], b0r[4], b1r[4];
#pragma unroll
    for (int m = 0; m < 4; ++m) {
      a0r[m] = *reinterpret_cast<const short8*>(&As[abase + m * 1024 + kx0]);
      a1r[m] = *reinterpret_cast<const short8*>(&As[abase + m * 1024 + kx1]);
    }
#pragma unroll
    for (int n = 0; n < 4; ++n) {
      b0r[n] = *reinterpret_cast<const short8*>(&Bs[bbase + n * 1024 + kx0]);
      b1r[n] = *reinterpret_cast<const short8*>(&Bs[bbase + n * 1024 + kx1]);
    }
    __builtin_amdgcn_s_setprio(1);
#pragma unroll
    for (int m = 0; m < 4; ++m)
#pragma unroll
      for (int n = 0; n < 4; ++n) {
        acc[m][n] = __builtin_amdgcn_mfma_f32_16x16x32_bf16(a0r[m], b0r[n], acc[m][n], 0, 0, 0);
        acc[m][n] = __builtin_amdgcn_mfma_f32_16x16x32_bf16(a1r[m], b1r[n], acc[m][n], 0, 0, 0);
      }
    __builtin_amdgcn_s_setprio(0);
    __syncthreads();
  }

  const int lq = lane >> 4;
#pragma unroll
  for (int m = 0; m < 4; ++m) {
#pragma unroll
    for (int n = 0; n < 4; ++n) {
#pragma unroll
      for (int i = 0; i < 4; ++i) {
        const long r = bm + wm * 64 + m * 16 + lq * 4 + i;
        const long c = bn + wn * 64 + n * 16 + l15;
        float val = acc[m][n][i];
        if constexpr (EPI == EPI_SBF16) {        // scores, scaled bf16
          ((ushort*)Cp)[(long)blockIdx.z * sC + r * (long)ldc + c] =
              (ushort)f2bf(val * scale);
        } else if constexpr (EPI == EPI_PV) {
          ((ushort*)Cp)[(long)blockIdx.z * sC + r * (long)ldc + c] = (ushort)f2bf(val);
        } else if constexpr (EPI == EPI_VT) {    // vT: row-bias (bv[e])
          val += bias[r];
          ((ushort*)Cp)[(long)blockIdx.z * sC + r * (long)ldc + c] = (ushort)f2bf(val);
        }
      }
    }
  }
}

// out = p0 + p1 + bias + res  (f32, 8 elems/thread, N=2048 columns)
__global__ __launch_bounds__(256)
void reduce2(const float* __restrict__ p0, const float* __restrict__ p1,
             const float* __restrict__ bias, const float* __restrict__ res,
             float* __restrict__ out)
{
  const long i = ((long)blockIdx.x * 256 + threadIdx.x) * 8;
  const int c = (int)(i & 2047);
  float4 a0 = *(const float4*)(p0 + i),  a1 = *(const float4*)(p0 + i + 4);
  float4 q0 = *(const float4*)(p1 + i),  q1 = *(const float4*)(p1 + i + 4);
  float4 r0 = *(const float4*)(res + i), r1 = *(const float4*)(res + i + 4);
  float4 b0 = *(const float4*)(bias + c), b1 = *(const float4*)(bias + c + 4);
  float4 o0 = {a0.x + q0.x + r0.x + b0.x, a0.y + q0.y + r0.y + b0.y,
               a0.z + q0.z + r0.z + b0.z, a0.w + q0.w + r0.w + b0.w};
  float4 o1 = {a1.x + q1.x + r1.x + b1.x, a1.y + q1.y + r1.y + b1.y,
               a1.z + q1.z + r1.z + b1.z, a1.w + q1.w + r1.w + b1.w};
  *(float4*)(out + i) = o0;
  *(float4*)(out + i + 4) = o1;
}

__global__ __launch_bounds__(256)
void cvt8(const float* __restrict__ s, ushort* __restrict__ d) {
  const long i = ((long)blockIdx.x * 256 + threadIdx.x) * 8;
  float4 a = *reinterpret_cast<const float4*>(s + i);
  float4 b = *reinterpret_cast<const float4*>(s + i + 4);
  short8 v;
  v[0] = f2bf(a.x); v[1] = f2bf(a.y); v[2] = f2bf(a.z); v[3] = f2bf(a.w);
  v[4] = f2bf(b.x); v[5] = f2bf(b.y); v[6] = f2bf(b.z); v[7] = f2bf(b.w);
  *reinterpret_cast<short8*>(d + i) = v;
}

__global__ __launch_bounds__(256)
void concat2(const float* __restrict__ b0, const float* __restrict__ b1,
             float* __restrict__ dst) {
  const int i = blockIdx.x * 256 + threadIdx.x;  // 4096 total
  dst[i] = (i < 2048) ? b0[i] : b1[i - 2048];
}

// row softmax over bf16 scores: [4096][2048] bf16 -> probs bf16
__global__ __launch_bounds__(256)
void softmax_rows(const ushort* __restrict__ S, ushort* __restrict__ P) {
  const long row = blockIdx.x;
  const ushort* src = S + row * 2048;
  const int t = threadIdx.x, lane = t & 63, wid = t >> 6;
  short8 raw = *reinterpret_cast<const short8*>(src + t * 8);
  float v[8];
#pragma unroll
  for (int i = 0; i < 8; ++i) v[i] = bf2f((ushort)raw[i]);
  float m = v[0];
#pragma unroll
  for (int i = 1; i < 8; ++i) m = fmaxf(m, v[i]);
#pragma unroll
  for (int o = 32; o; o >>= 1) m = fmaxf(m, __shfl_xor(m, o));
  __shared__ float rm[4], rs[4];
  if (!lane) rm[wid] = m;
  __syncthreads();
  m = fmaxf(fmaxf(rm[0], rm[1]), fmaxf(rm[2], rm[3]));
  float e[8], s = 0.f;
#pragma unroll
  for (int i = 0; i < 8; ++i) { e[i] = __expf(v[i] - m); s += e[i]; }
#pragma unroll
  for (int o = 32; o; o >>= 1) s += __shfl_xor(s, o);
  if (!lane) rs[wid] = s;
  __syncthreads();
  s = rs[0] + rs[1] + rs[2] + rs[3];
  const float inv = 1.0f / s;
  short8 wv;
#pragma unroll
  for (int i = 0; i < 8; ++i) wv[i] = f2bf(e[i] * inv);
  *reinterpret_cast<short8*>(P + row * 2048 + t * 8) = wv;
}

// layernorm of (p0 + p1 + bias + res), emitting f32 H and bf16 Hb.
__global__ __launch_bounds__(256)
void layernorm_fused(const float* __restrict__ p0, const float* __restrict__ p1,
                     const float* __restrict__ bias, const float* __restrict__ res,
                     const float* __restrict__ g, const float* __restrict__ bb,
                     float* __restrict__ H, ushort* __restrict__ Hb) {
  const long row = blockIdx.x;
  const long base = row * 2048;
  const int t = threadIdx.x, lane = t & 63, wid = t >> 6;
  const long i = base + t * 8;
  const int c0 = t * 8;
  float v[8];
  {
    float4 a0 = *(const float4*)(p0 + i),  a1 = *(const float4*)(p0 + i + 4);
    float4 q0 = *(const float4*)(p1 + i),  q1 = *(const float4*)(p1 + i + 4);
    float4 r0 = *(const float4*)(res + i), r1 = *(const float4*)(res + i + 4);
    float4 b0 = *(const float4*)(bias + c0), b1 = *(const float4*)(bias + c0 + 4);
    v[0] = a0.x + q0.x + r0.x + b0.x; v[1] = a0.y + q0.y + r0.y + b0.y;
    v[2] = a0.z + q0.z + r0.z + b0.z; v[3] = a0.w + q0.w + r0.w + b0.w;
    v[4] = a1.x + q1.x + r1.x + b1.x; v[5] = a1.y + q1.y + r1.y + b1.y;
    v[6] = a1.z + q1.z + r1.z + b1.z; v[7] = a1.w + q1.w + r1.w + b1.w;
  }
  float s = 0.f, ss = 0.f;
#pragma unroll
  for (int i2 = 0; i2 < 8; ++i2) { s += v[i2]; ss += v[i2] * v[i2]; }
#pragma unroll
  for (int o = 32; o; o >>= 1) { s += __shfl_xor(s, o); ss += __shfl_xor(ss, o); }
  __shared__ float r1s[4], r2s[4];
  if (!lane) { r1s[wid] = s; r2s[wid] = ss; }
  __syncthreads();
  s = r1s[0] + r1s[1] + r1s[2] + r1s[3];
  ss = r2s[0] + r2s[1] + r2s[2] + r2s[3];
  const float mu = s * (1.0f / 2048.0f);
  const float var = ss * (1.0f / 2048.0f) - mu * mu;
  const float inv = rsqrtf(var + 1e-5f);
  float o0[8];
  short8 wv;
#pragma unroll
  for (int i2 = 0; i2 < 8; ++i2) {
    const int c = c0 + i2;
    o0[i2] = (v[i2] - mu) * inv * g[c] + bb[c];
    wv[i2] = f2bf(o0[i2]);
  }
  float4 w0 = {o0[0], o0[1], o0[2], o0[3]}, w1 = {o0[4], o0[5], o0[6], o0[7]};
  *reinterpret_cast<float4*>(H + i) = w0;
  *reinterpret_cast<float4*>(H + i + 4) = w1;
  *reinterpret_cast<short8*>(Hb + i) = wv;
}

extern "C" void kernel_launch(void* const* d_in, const int* in_sizes, int n_in,
                              void* d_out, int out_size, void* d_ws, size_t ws_size,
                              hipStream_t stream) {
  const float* x    = (const float*)d_in[0];
  const float* wq   = (const float*)d_in[1];
  const float* bq   = (const float*)d_in[2];
  const float* wk   = (const float*)d_in[3];
  const float* bk   = (const float*)d_in[4];
  const float* wv   = (const float*)d_in[5];
  const float* bv   = (const float*)d_in[6];
  const float* wd   = (const float*)d_in[7];
  const float* bd   = (const float*)d_in[8];
  const float* ln_g = (const float*)d_in[9];
  const float* ln_b = (const float*)d_in[10];
  const float* w1   = (const float*)d_in[11];
  const float* b1   = (const float*)d_in[12];
  const float* w2   = (const float*)d_in[13];
  const float* b2   = (const float*)d_in[14];
  float* out = (float*)d_out;

  (void)hipFuncSetAttribute((const void*)&gemm256<EPI_QKV>,
      hipFuncAttributeMaxDynamicSharedMemorySize, 131072);
  (void)hipFuncSetAttribute((const void*)&gemm256<EPI_GELU>,
      hipFuncAttributeMaxDynamicSharedMemorySize, 131072);
  (void)hipFuncSetAttribute((const void*)&gemm256<EPI_SCORES>,
      hipFuncAttributeMaxDynamicSharedMemorySize, 131072);

  // ---- workspace layout (233 MiB, aliased; liveness audited) ----
  char* p = (char*)d_ws;
  const size_t MB = 1048576;
  ushort* wdb    = (ushort*)(p + 0 * MB);     // 8 MB   [dead after attn-out]
  ushort* w1b    = (ushort*)(p + 8 * MB);     // 32 MB  [dead after mlp1]
  ushort* w2b    = (ushort*)(p + 40 * MB);    // 32 MB  [live till mlp2]
  float*  bqk    = (float*) (p + 72 * MB);    // 16 KB
  ushort* xb     = (ushort*)(p + 73 * MB);    // 16 MB  [dead after vT] -> probs
  ushort* probs  = xb;
  ushort* qk     = (ushort*)(p + 89 * MB);    // 32 MB  [dead after scores]
  ushort* wqkb   = (ushort*)(p + 121 * MB);   // 16 MB  [dead after QK]
  ushort* vT     = (ushort*)(p + 121 * MB);   // 16 MB  [dead after PV]
  ushort* wvb    = (ushort*)(p + 137 * MB);   // 8 MB   [dead after vT]
  ushort* scoresb= (ushort*)(p + 137 * MB);   // 16 MB  [dead after softmax]
  float*  partA  = (float*) (p + 89 * MB);    // 64 MB (89-153) attn-out out
  ushort* mlpb   = (ushort*)(p + 89 * MB);    // 64 MB  mlp1 out
  float*  h      = (float*) (p + 153 * MB);   // 32 MB  [live till end]
  ushort* hb     = (ushort*)(p + 185 * MB);   // 16 MB  [dead after mlp1]
  ushort* ctx    = (ushort*)(p + 201 * MB);   // 16 MB  [dead after attn-out]
  float*  partM0 = (float*) (p + 0 * MB);     // 32 MB  (wdb/w1b dead)
  float*  partM1 = (float*) (p + 201 * MB);   // 32 MB  (ctx dead)

  const dim3 blk(256), blk512(512);
  const long SQ = (long)SEQ * SEQ;

  // ---- bf16 conversions ----
  cvt8<<<4096, blk, 0, stream>>>(x, xb);
  cvt8<<<2048, blk, 0, stream>>>(wq, wqkb);
  cvt8<<<2048, blk, 0, stream>>>(wk, wqkb + 4194304);
  cvt8<<<2048, blk, 0, stream>>>(wv, wvb);
  cvt8<<<2048, blk, 0, stream>>>(wd, wdb);
  cvt8<<<8192, blk, 0, stream>>>(w1, w1b);
  cvt8<<<8192, blk, 0, stream>>>(w2, w2b);
  concat2<<<16, blk, 0, stream>>>(bq, bk, bqk);

  // QK: [4096,2048] x [4096,2048]^T -> qk bf16 [4096][4096] (1 full round)
  gemm256<EPI_QKV><<<dim3(16, 16, 1), blk512, 131072, stream>>>(
      xb, wqkb, bqk, qk, 4096, 2048, 2048, 2048, 4096, 0, 0, 0, 1.f);

  // vT[b][e][s] = wv[e]·x[b,s] + bv[e]  (direct transposed V)
  gemm_bt<EPI_VT><<<dim3(16, 16, 2), blk, 0, stream>>>(
      wvb, xb, bv, vT, 2048, 2048, 2048, 2048, 2048,
      0, SQ, SQ, 1.f);

  // scores = q k^T / sqrt(E) per batch -> bf16
  gemm_bt<EPI_SBF16><<<dim3(16, 16, 2), blk, 0, stream>>>(
      qk, qk + 2048, nullptr, scoresb, 2048, 2048, 4096, 4096, 2048,
      2048L * 4096, 2048L * 4096, SQ, 0.022097086912079608f);

  softmax_rows<<<dim3(4096), blk, 0, stream>>>(scoresb, probs);

  // ctx = probs @ v
  gemm_bt<EPI_PV><<<dim3(16, 16, 2), blk, 0, stream>>>(
      probs, vT, nullptr, ctx, 2048, 2048, 2048, 2048, 2048,
      SQ, SQ, SQ, 1.f);

  // attn-out, split-K=2: partA[z] = ctx[:, z*1024:+1024] @ wd^T-slice
  gemm256<EPI_SCORES><<<dim3(8, 16, 2), blk512, 131072, stream>>>(
      ctx, wdb, nullptr, partA, 2048, 1024, 2048, 2048, 2048,
      1024, 1024, 8388608, 1.f);

  // h = LN(partA0 + partA1 + bd + x); hb = bf16(h)
  layernorm_fused<<<4096, blk, 0, stream>>>(
      partA, partA + 8388608, bd, x, ln_g, ln_b, h, hb);

  // mlpb = gelu(h @ w1^T + b1)
  gemm256<EPI_GELU><<<dim3(32, 16, 1), blk512, 131072, stream>>>(
      hb, w1b, b1, mlpb, 8192, 2048, 2048, 2048, 8192, 0, 0, 0, 1.f);

  // mlp2, split-K=2: partM[z] = mlpb[:, z*4096:+4096] @ w2^T-slice
  gemm256<EPI_SCORES><<<dim3(8, 16, 2), blk512, 131072, stream>>>(
      mlpb, w2b, nullptr, partM0, 2048, 4096, 8192, 8192, 2048,
      4096, 4096, (long)(201 * MB / 4), 1.f);
  // out = partM0 + partM1 + b2 + h
  reduce2<<<4096, blk, 0, stream>>>(partM0, partM1, b2, h, out);
}

// Round 15
// 609.815 us; speedup vs baseline: 1.1605x; 1.0263x over previous
//
#include <hip/hip_runtime.h>
#include <math.h>

// PhiDecoderLayer on MI355X. B=2, S=2048, E=2048, MLP=8192, fp32 in/out.
// Round 15: r14 (626us) with the 8-kernel conversion preamble fused into a
// single grid-strided cvt_all dispatch (segment table, block-uniform branch;
// bias concat folded into the same launch). GEMM kernels untouched.

#define SEQ 2048
#define EMB 2048
#define MLPD 8192

typedef __attribute__((ext_vector_type(8))) short short8;
typedef __attribute__((ext_vector_type(4))) float floatx4;
typedef unsigned short ushort;

__device__ __forceinline__ short f2bf(float f) {
  union { float f; unsigned u; } v; v.f = f;
  unsigned r = v.u + 0x7FFFu + ((v.u >> 16) & 1u);
  return (short)(r >> 16);
}
__device__ __forceinline__ float bf2f(ushort u) {
  union { unsigned u; float f; } v; v.u = ((unsigned)u) << 16;
  return v.f;
}

// async global->LDS, 16B per lane. LDS dest = wave-uniform base + lane*16.
__device__ __forceinline__ void gload16(const ushort* g, ushort* l) {
  __builtin_amdgcn_global_load_lds(
      (__attribute__((address_space(1))) void*)g,
      (__attribute__((address_space(3))) void*)(unsigned)(unsigned long)l,
      16, 0, 0);
}

enum { EPI_QKV = 0, EPI_SCORES = 1, EPI_PV = 2, EPI_GELU = 4,
       EPI_VT = 5, EPI_SBF16 = 6 };

// ============================================================================
// 256x256 tile, BK=64, 8 waves — r10 structure (one barrier per phase).
// ============================================================================
template<int EPI>
__global__ __launch_bounds__(512, 2)
void gemm256(const ushort* __restrict__ A, const ushort* __restrict__ B,
             const float* __restrict__ bias, void* __restrict__ Cp,
             int N, int K, int lda, int ldb, int ldc,
             long sA, long sB, long sC, float scale)
{
  extern __shared__ ushort lds[];   // 65536 ushorts = 128 KiB
  const int t = threadIdx.x;
  const int lane = t & 63, w = t >> 6;
  const int wm = w >> 2, wn = w & 3;
  const long bm = (long)blockIdx.y * 256;
  const long bn = (long)blockIdx.x * 256;
  A += (long)blockIdx.z * sA;
  B += (long)blockIdx.z * sB;

  const int srow = (w << 3) + (lane >> 3);
  const int gcol = (lane & 7) ^ ((lane >> 3) & 7);
  const ushort* Ab = A + (bm + srow) * (long)lda + gcol * 8;
  const ushort* Bb = B + (bn + srow) * (long)ldb + gcol * 8;
  ushort* lw = lds + (w << 9);

#define STG_A0(LOFF, KK) do { gload16(Ab + (KK), lw + (LOFF)); \
    gload16(Ab + 64L * lda + (KK), lw + (LOFF) + 4096); } while (0)
#define STG_A1(LOFF, KK) do { gload16(Ab + 128L * lda + (KK), lw + (LOFF)); \
    gload16(Ab + 192L * lda + (KK), lw + (LOFF) + 4096); } while (0)
#define STG_B0(LOFF, KK) do { gload16(Bb + (KK), lw + (LOFF)); \
    gload16(Bb + 64L * ldb + (KK), lw + (LOFF) + 4096); } while (0)
#define STG_B1(LOFF, KK) do { gload16(Bb + 128L * ldb + (KK), lw + (LOFF)); \
    gload16(Bb + 192L * ldb + (KK), lw + (LOFF) + 4096); } while (0)

  const int l15 = lane & 15, q = lane >> 4, swz = l15 & 7;
  const int kx0 = (q ^ swz) << 3;
  const int kx1 = ((4 + q) ^ swz) << 3;
  const int arow = (wm << 13) + l15 * 64;
  const int brow = 16384 + ((wn >> 1) << 13) + ((wn & 1) << 12) + l15 * 64;

  floatx4 acc[8][4];
#pragma unroll
  for (int m = 0; m < 8; ++m)
#pragma unroll
    for (int n = 0; n < 4; ++n) acc[m][n] = (floatx4)0.0f;

  short8 A0[4], A1[4], B0[4], B1[4];

#define LDS8(IDX) (*(const short8*)&lds[IDX])
#define RD_ALK0(CB) do { _Pragma("unroll") for (int mf = 0; mf < 4; ++mf) \
    A0[mf] = LDS8((CB) + arow + mf * 1024 + kx0); } while (0)
#define RD_ALK1(CB) do { _Pragma("unroll") for (int mf = 0; mf < 4; ++mf) \
    A1[mf] = LDS8((CB) + arow + mf * 1024 + kx1); } while (0)
#define RD_AHK0(CB) do { _Pragma("unroll") for (int mf = 0; mf < 4; ++mf) \
    A0[mf] = LDS8((CB) + arow + (4 + mf) * 1024 + kx0); } while (0)
#define RD_AHK1(CB) do { _Pragma("unroll") for (int mf = 0; mf < 4; ++mf) \
    A1[mf] = LDS8((CB) + arow + (4 + mf) * 1024 + kx1); } while (0)
#define RD_BK0(CB) do { _Pragma("unroll") for (int nf = 0; nf < 4; ++nf) \
    B0[nf] = LDS8((CB) + brow + nf * 1024 + kx0); } while (0)
#define RD_BK1(CB) do { _Pragma("unroll") for (int nf = 0; nf < 4; ++nf) \
    B1[nf] = LDS8((CB) + brow + nf * 1024 + kx1); } while (0)

#define MMA16(MO, AX, BX) do {                                            \
    __builtin_amdgcn_s_setprio(1);                                        \
    _Pragma("unroll") for (int mf = 0; mf < 4; ++mf)                      \
      _Pragma("unroll") for (int nf = 0; nf < 4; ++nf)                    \
        acc[(MO)+mf][nf] = __builtin_amdgcn_mfma_f32_16x16x32_bf16(       \
            AX[mf], BX[nf], acc[(MO)+mf][nf], 0, 0, 0);                   \
    __builtin_amdgcn_s_setprio(0);                                        \
  } while (0)

#define BARR() __builtin_amdgcn_s_barrier()
#define VMC4  asm volatile("s_waitcnt vmcnt(4)" ::: "memory")

#define KTILE(CB, NB, K1, K2) do {                                        \
    RD_ALK0(CB); RD_BK0(CB); STG_A0((NB) + 0, K1);                        \
    MMA16(0, A0, B0); BARR();                                             \
    RD_ALK1(CB); RD_BK1(CB); STG_A1((NB) + 8192, K1);                     \
    MMA16(0, A1, B1); BARR();                                             \
    RD_AHK0(CB); STG_B0((CB) + 16384, K2);                                \
    MMA16(4, A0, B0); BARR();                                             \
    RD_AHK1(CB); STG_B1((CB) + 24576, K2);                                \
    MMA16(4, A1, B1); VMC4; BARR();                                       \
  } while (0)

  STG_A0(0, 0);              STG_A1(8192, 0);
  STG_B0(16384, 0);          STG_B1(24576, 0);
  {
    const int k1p = (K > 64) ? 64 : 0;
    STG_B0(32768 + 16384, k1p);
    STG_B1(32768 + 24576, k1p);
  }
  asm volatile("s_waitcnt vmcnt(4)" ::: "memory");
  BARR();

  const int NT = K >> 6;
  for (int kt = 0; kt < NT; kt += 2) {
    const int k1 = ((kt + 1 < NT) ? kt + 1 : NT - 1) << 6;
    const int k2 = ((kt + 2 < NT) ? kt + 2 : NT - 1) << 6;
    const int k3 = ((kt + 3 < NT) ? kt + 3 : NT - 1) << 6;
    KTILE(0,     32768, k1, k2);
    KTILE(32768, 0,     k2, k3);
  }
  asm volatile("s_waitcnt vmcnt(0)" ::: "memory");
#undef KTILE
#undef MMA16
#undef RD_ALK0
#undef RD_ALK1
#undef RD_AHK0
#undef RD_AHK1
#undef RD_BK0
#undef RD_BK1
#undef LDS8
#undef STG_A0
#undef STG_A1
#undef STG_B0
#undef STG_B1

  const int lq = lane >> 4;
#pragma unroll
  for (int mf = 0; mf < 8; ++mf) {
#pragma unroll
    for (int nf = 0; nf < 4; ++nf) {
#pragma unroll
      for (int i = 0; i < 4; ++i) {
        const long r = bm + wm * 128 + mf * 16 + lq * 4 + i;
        const long c = bn + wn * 64 + nf * 16 + l15;
        float val = acc[mf][nf][i];
        if constexpr (EPI == EPI_QKV) {
          val += bias[c];
          ((ushort*)Cp)[r * (long)ldc + c] = (ushort)f2bf(val);
        } else if constexpr (EPI == EPI_SCORES) {  // raw f32 partial
          ((float*)Cp)[(long)blockIdx.z * sC + r * (long)ldc + c] = val * scale;
        } else {  // EPI_GELU exact
          val += bias[c];
          float g = 0.5f * val * (1.0f + erff(val * 0.70710678118f));
          ((ushort*)Cp)[r * (long)ldc + c] = (ushort)f2bf(g);
        }
      }
    }
  }
}

// ============================================================================
// 128x128 tile, BK=64, 4 waves (2Mx2N), single-buffered, swizzled LDS.
// Used for scores (bf16 out), PV, and direct-V^T.
// ============================================================================
template<int EPI>
__global__ __launch_bounds__(256)
void gemm_bt(const ushort* __restrict__ A, const ushort* __restrict__ B,
             const float* __restrict__ bias, void* __restrict__ Cp,
             int N, int K, int lda, int ldb, int ldc,
             long sA, long sB, long sC, float scale)
{
  __shared__ ushort As[128 * 64];   // 16 KiB
  __shared__ ushort Bs[128 * 64];   // 16 KiB

  const int t = threadIdx.x;
  const int lane = t & 63, wid = t >> 6;
  const int wm = wid >> 1, wn = wid & 1;
  const long bm = (long)blockIdx.y * 128;
  const long bn = (long)blockIdx.x * 128;
  A += (long)blockIdx.z * sA;
  B += (long)blockIdx.z * sB;

  const int srow = (wid << 3) + (lane >> 3);            // 0..31
  const int gcol = (lane & 7) ^ ((lane >> 3) & 7);      // pre-swizzled granule
  const ushort* a0 = A + (bm + srow) * (long)lda + gcol * 8;
  const ushort* b0 = B + (bn + srow) * (long)ldb + gcol * 8;
  ushort* lA = As + (wid << 9);
  ushort* lB = Bs + (wid << 9);

  floatx4 acc[4][4];
#pragma unroll
  for (int m = 0; m < 4; ++m)
#pragma unroll
    for (int n = 0; n < 4; ++n) acc[m][n] = (floatx4)0.0f;

  const int l15 = lane & 15, q = lane >> 4, swz = l15 & 7;
  const int kx0 = (q ^ swz) << 3;
  const int kx1 = ((4 + q) ^ swz) << 3;
  const int abase = ((wm << 6) + l15) * 64;
  const int bbase = ((wn << 6) + l15) * 64;

  for (int kb = 0; kb < K; kb += 64) {
#pragma unroll
    for (int i = 0; i < 4; ++i) {
      gload16(a0 + (32L * i) * lda + kb, lA + i * 2048);
      gload16(b0 + (32L * i) * ldb + kb, lB + i * 2048);
    }
    __syncthreads();

    short8 a0r[4], a1r[4], b0r[4], b1r[4];
#pragma unroll
    for (int m = 0; m < 4; ++m) {
      a0r[m] = *reinterpret_cast<const short8*>(&As[abase + m * 1024 + kx0]);
      a1r[m] = *reinterpret_cast<const short8*>(&As[abase + m * 1024 + kx1]);
    }
#pragma unroll
    for (int n = 0; n < 4; ++n) {
      b0r[n] = *reinterpret_cast<const short8*>(&Bs[bbase + n * 1024 + kx0]);
      b1r[n] = *reinterpret_cast<const short8*>(&Bs[bbase + n * 1024 + kx1]);
    }
    __builtin_amdgcn_s_setprio(1);
#pragma unroll
    for (int m = 0; m < 4; ++m)
#pragma unroll
      for (int n = 0; n < 4; ++n) {
        acc[m][n] = __builtin_amdgcn_mfma_f32_16x16x32_bf16(a0r[m], b0r[n], acc[m][n], 0, 0, 0);
        acc[m][n] = __builtin_amdgcn_mfma_f32_16x16x32_bf16(a1r[m], b1r[n], acc[m][n], 0, 0, 0);
      }
    __builtin_amdgcn_s_setprio(0);
    __syncthreads();
  }

  const int lq = lane >> 4;
#pragma unroll
  for (int m = 0; m < 4; ++m) {
#pragma unroll
    for (int n = 0; n < 4; ++n) {
#pragma unroll
      for (int i = 0; i < 4; ++i) {
        const long r = bm + wm * 64 + m * 16 + lq * 4 + i;
        const long c = bn + wn * 64 + n * 16 + l15;
        float val = acc[m][n][i];
        if constexpr (EPI == EPI_SBF16) {        // scores, scaled bf16
          ((ushort*)Cp)[(long)blockIdx.z * sC + r * (long)ldc + c] =
              (ushort)f2bf(val * scale);
        } else if constexpr (EPI == EPI_PV) {
          ((ushort*)Cp)[(long)blockIdx.z * sC + r * (long)ldc + c] = (ushort)f2bf(val);
        } else if constexpr (EPI == EPI_VT) {    // vT: row-bias (bv[e])
          val += bias[r];
          ((ushort*)Cp)[(long)blockIdx.z * sC + r * (long)ldc + c] = (ushort)f2bf(val);
        }
      }
    }
  }
}

// ============================================================================
// Fused conversion: all fp32->bf16 weight/activation conversions + bias
// concat in ONE dispatch. Segment boundaries are multiples of 2048 elements,
// so each 256-thread block (2048 elems) is wholly inside one segment.
// ============================================================================
struct CvtSeg { const float* src; ushort* dst; long end; };

__global__ __launch_bounds__(256)
void cvt_all(const float* x,  ushort* xb,
             const float* wq, const float* wk, ushort* wqkb,
             const float* wv, ushort* wvb,
             const float* wd, ushort* wdb,
             const float* w1, ushort* w1b,
             const float* w2, ushort* w2b,
             const float* bq, const float* bk, float* bqk)
{
  // bias concat folded into the first 16 blocks (4096 floats)
  if (blockIdx.x < 16) {
    const int i = blockIdx.x * 256 + threadIdx.x;
    bqk[i] = (i < 2048) ? bq[i] : bk[i - 2048];
  }
  const long gi = ((long)blockIdx.x * 256 + threadIdx.x) * 8;
  const float* src;
  ushort* dst;
  long off;
  if (gi < 8388608L)        { src = x;  dst = xb;             off = 0; }
  else if (gi < 12582912L)  { src = wq; dst = wqkb;           off = 8388608L; }
  else if (gi < 16777216L)  { src = wk; dst = wqkb + 4194304; off = 12582912L; }
  else if (gi < 20971520L)  { src = wv; dst = wvb;            off = 16777216L; }
  else if (gi < 25165824L)  { src = wd; dst = wdb;            off = 20971520L; }
  else if (gi < 41943040L)  { src = w1; dst = w1b;            off = 25165824L; }
  else                      { src = w2; dst = w2b;            off = 41943040L; }
  const long i = gi - off;
  float4 a = *reinterpret_cast<const float4*>(src + i);
  float4 b = *reinterpret_cast<const float4*>(src + i + 4);
  short8 v;
  v[0] = f2bf(a.x); v[1] = f2bf(a.y); v[2] = f2bf(a.z); v[3] = f2bf(a.w);
  v[4] = f2bf(b.x); v[5] = f2bf(b.y); v[6] = f2bf(b.z); v[7] = f2bf(b.w);
  *reinterpret_cast<short8*>(dst + i) = v;
}

// out = p0 + p1 + bias + res  (f32, 8 elems/thread, N=2048 columns)
__global__ __launch_bounds__(256)
void reduce2(const float* __restrict__ p0, const float* __restrict__ p1,
             const float* __restrict__ bias, const float* __restrict__ res,
             float* __restrict__ out)
{
  const long i = ((long)blockIdx.x * 256 + threadIdx.x) * 8;
  const int c = (int)(i & 2047);
  float4 a0 = *(const float4*)(p0 + i),  a1 = *(const float4*)(p0 + i + 4);
  float4 q0 = *(const float4*)(p1 + i),  q1 = *(const float4*)(p1 + i + 4);
  float4 r0 = *(const float4*)(res + i), r1 = *(const float4*)(res + i + 4);
  float4 b0 = *(const float4*)(bias + c), b1 = *(const float4*)(bias + c + 4);
  float4 o0 = {a0.x + q0.x + r0.x + b0.x, a0.y + q0.y + r0.y + b0.y,
               a0.z + q0.z + r0.z + b0.z, a0.w + q0.w + r0.w + b0.w};
  float4 o1 = {a1.x + q1.x + r1.x + b1.x, a1.y + q1.y + r1.y + b1.y,
               a1.z + q1.z + r1.z + b1.z, a1.w + q1.w + r1.w + b1.w};
  *(float4*)(out + i) = o0;
  *(float4*)(out + i + 4) = o1;
}

// row softmax over bf16 scores: [4096][2048] bf16 -> probs bf16
__global__ __launch_bounds__(256)
void softmax_rows(const ushort* __restrict__ S, ushort* __restrict__ P) {
  const long row = blockIdx.x;
  const ushort* src = S + row * 2048;
  const int t = threadIdx.x, lane = t & 63, wid = t >> 6;
  short8 raw = *reinterpret_cast<const short8*>(src + t * 8);
  float v[8];
#pragma unroll
  for (int i = 0; i < 8; ++i) v[i] = bf2f((ushort)raw[i]);
  float m = v[0];
#pragma unroll
  for (int i = 1; i < 8; ++i) m = fmaxf(m, v[i]);
#pragma unroll
  for (int o = 32; o; o >>= 1) m = fmaxf(m, __shfl_xor(m, o));
  __shared__ float rm[4], rs[4];
  if (!lane) rm[wid] = m;
  __syncthreads();
  m = fmaxf(fmaxf(rm[0], rm[1]), fmaxf(rm[2], rm[3]));
  float e[8], s = 0.f;
#pragma unroll
  for (int i = 0; i < 8; ++i) { e[i] = __expf(v[i] - m); s += e[i]; }
#pragma unroll
  for (int o = 32; o; o >>= 1) s += __shfl_xor(s, o);
  if (!lane) rs[wid] = s;
  __syncthreads();
  s = rs[0] + rs[1] + rs[2] + rs[3];
  const float inv = 1.0f / s;
  short8 wv;
#pragma unroll
  for (int i = 0; i < 8; ++i) wv[i] = f2bf(e[i] * inv);
  *reinterpret_cast<short8*>(P + row * 2048 + t * 8) = wv;
}

// layernorm of (p0 + p1 + bias + res), emitting f32 H and bf16 Hb.
__global__ __launch_bounds__(256)
void layernorm_fused(const float* __restrict__ p0, const float* __restrict__ p1,
                     const float* __restrict__ bias, const float* __restrict__ res,
                     const float* __restrict__ g, const float* __restrict__ bb,
                     float* __restrict__ H, ushort* __restrict__ Hb) {
  const long row = blockIdx.x;
  const long base = row * 2048;
  const int t = threadIdx.x, lane = t & 63, wid = t >> 6;
  const long i = base + t * 8;
  const int c0 = t * 8;
  float v[8];
  {
    float4 a0 = *(const float4*)(p0 + i),  a1 = *(const float4*)(p0 + i + 4);
    float4 q0 = *(const float4*)(p1 + i),  q1 = *(const float4*)(p1 + i + 4);
    float4 r0 = *(const float4*)(res + i), r1 = *(const float4*)(res + i + 4);
    float4 b0 = *(const float4*)(bias + c0), b1 = *(const float4*)(bias + c0 + 4);
    v[0] = a0.x + q0.x + r0.x + b0.x; v[1] = a0.y + q0.y + r0.y + b0.y;
    v[2] = a0.z + q0.z + r0.z + b0.z; v[3] = a0.w + q0.w + r0.w + b0.w;
    v[4] = a1.x + q1.x + r1.x + b1.x; v[5] = a1.y + q1.y + r1.y + b1.y;
    v[6] = a1.z + q1.z + r1.z + b1.z; v[7] = a1.w + q1.w + r1.w + b1.w;
  }
  float s = 0.f, ss = 0.f;
#pragma unroll
  for (int i2 = 0; i2 < 8; ++i2) { s += v[i2]; ss += v[i2] * v[i2]; }
#pragma unroll
  for (int o = 32; o; o >>= 1) { s += __shfl_xor(s, o); ss += __shfl_xor(ss, o); }
  __shared__ float r1s[4], r2s[4];
  if (!lane) { r1s[wid] = s; r2s[wid] = ss; }
  __syncthreads();
  s = r1s[0] + r1s[1] + r1s[2] + r1s[3];
  ss = r2s[0] + r2s[1] + r2s[2] + r2s[3];
  const float mu = s * (1.0f / 2048.0f);
  const float var = ss * (1.0f / 2048.0f) - mu * mu;
  const float inv = rsqrtf(var + 1e-5f);
  float o0[8];
  short8 wv;
#pragma unroll
  for (int i2 = 0; i2 < 8; ++i2) {
    const int c = c0 + i2;
    o0[i2] = (v[i2] - mu) * inv * g[c] + bb[c];
    wv[i2] = f2bf(o0[i2]);
  }
  float4 w0 = {o0[0], o0[1], o0[2], o0[3]}, w1 = {o0[4], o0[5], o0[6], o0[7]};
  *reinterpret_cast<float4*>(H + i) = w0;
  *reinterpret_cast<float4*>(H + i + 4) = w1;
  *reinterpret_cast<short8*>(Hb + i) = wv;
}

extern "C" void kernel_launch(void* const* d_in, const int* in_sizes, int n_in,
                              void* d_out, int out_size, void* d_ws, size_t ws_size,
                              hipStream_t stream) {
  const float* x    = (const float*)d_in[0];
  const float* wq   = (const float*)d_in[1];
  const float* bq   = (const float*)d_in[2];
  const float* wk   = (const float*)d_in[3];
  const float* bk   = (const float*)d_in[4];
  const float* wv   = (const float*)d_in[5];
  const float* bv   = (const float*)d_in[6];
  const float* wd   = (const float*)d_in[7];
  const float* bd   = (const float*)d_in[8];
  const float* ln_g = (const float*)d_in[9];
  const float* ln_b = (const float*)d_in[10];
  const float* w1   = (const float*)d_in[11];
  const float* b1   = (const float*)d_in[12];
  const float* w2   = (const float*)d_in[13];
  const float* b2   = (const float*)d_in[14];
  float* out = (float*)d_out;

  (void)hipFuncSetAttribute((const void*)&gemm256<EPI_QKV>,
      hipFuncAttributeMaxDynamicSharedMemorySize, 131072);
  (void)hipFuncSetAttribute((const void*)&gemm256<EPI_GELU>,
      hipFuncAttributeMaxDynamicSharedMemorySize, 131072);
  (void)hipFuncSetAttribute((const void*)&gemm256<EPI_SCORES>,
      hipFuncAttributeMaxDynamicSharedMemorySize, 131072);

  // ---- workspace layout (233 MiB, aliased; liveness audited) ----
  char* p = (char*)d_ws;
  const size_t MB = 1048576;
  ushort* wdb    = (ushort*)(p + 0 * MB);     // 8 MB   [dead after attn-out]
  ushort* w1b    = (ushort*)(p + 8 * MB);     // 32 MB  [dead after mlp1]
  ushort* w2b    = (ushort*)(p + 40 * MB);    // 32 MB  [live till mlp2]
  float*  bqk    = (float*) (p + 72 * MB);    // 16 KB
  ushort* xb     = (ushort*)(p + 73 * MB);    // 16 MB  [dead after vT] -> probs
  ushort* probs  = xb;
  ushort* qk     = (ushort*)(p + 89 * MB);    // 32 MB  [dead after scores]
  ushort* wqkb   = (ushort*)(p + 121 * MB);   // 16 MB  [dead after QK]
  ushort* vT     = (ushort*)(p + 121 * MB);   // 16 MB  [dead after PV]
  ushort* wvb    = (ushort*)(p + 137 * MB);   // 8 MB   [dead after vT]
  ushort* scoresb= (ushort*)(p + 137 * MB);   // 16 MB  [dead after softmax]
  float*  partA  = (float*) (p + 89 * MB);    // 64 MB (89-153) attn-out out
  ushort* mlpb   = (ushort*)(p + 89 * MB);    // 64 MB  mlp1 out
  float*  h      = (float*) (p + 153 * MB);   // 32 MB  [live till end]
  ushort* hb     = (ushort*)(p + 185 * MB);   // 16 MB  [dead after mlp1]
  ushort* ctx    = (ushort*)(p + 201 * MB);   // 16 MB  [dead after attn-out]
  float*  partM0 = (float*) (p + 0 * MB);     // 32 MB  (wdb/w1b dead)
  float*  partM1 = (float*) (p + 201 * MB);   // 32 MB  (ctx dead)

  const dim3 blk(256), blk512(512);
  const long SQ = (long)SEQ * SEQ;

  // ---- one fused conversion dispatch (7 tensors + bias concat) ----
  cvt_all<<<28672, blk, 0, stream>>>(
      x, xb, wq, wk, wqkb, wv, wvb, wd, wdb, w1, w1b, w2, w2b, bq, bk, bqk);

  // QK: [4096,2048] x [4096,2048]^T -> qk bf16 [4096][4096] (1 full round)
  gemm256<EPI_QKV><<<dim3(16, 16, 1), blk512, 131072, stream>>>(
      xb, wqkb, bqk, qk, 4096, 2048, 2048, 2048, 4096, 0, 0, 0, 1.f);

  // vT[b][e][s] = wv[e]·x[b,s] + bv[e]  (direct transposed V)
  gemm_bt<EPI_VT><<<dim3(16, 16, 2), blk, 0, stream>>>(
      wvb, xb, bv, vT, 2048, 2048, 2048, 2048, 2048,
      0, SQ, SQ, 1.f);

  // scores = q k^T / sqrt(E) per batch -> bf16
  gemm_bt<EPI_SBF16><<<dim3(16, 16, 2), blk, 0, stream>>>(
      qk, qk + 2048, nullptr, scoresb, 2048, 2048, 4096, 4096, 2048,
      2048L * 4096, 2048L * 4096, SQ, 0.022097086912079608f);

  softmax_rows<<<dim3(4096), blk, 0, stream>>>(scoresb, probs);

  // ctx = probs @ v
  gemm_bt<EPI_PV><<<dim3(16, 16, 2), blk, 0, stream>>>(
      probs, vT, nullptr, ctx, 2048, 2048, 2048, 2048, 2048,
      SQ, SQ, SQ, 1.f);

  // attn-out, split-K=2: partA[z] = ctx[:, z*1024:+1024] @ wd^T-slice
  gemm256<EPI_SCORES><<<dim3(8, 16, 2), blk512, 131072, stream>>>(
      ctx, wdb, nullptr, partA, 2048, 1024, 2048, 2048, 2048,
      1024, 1024, 8388608, 1.f);

  // h = LN(partA0 + partA1 + bd + x); hb = bf16(h)
  layernorm_fused<<<4096, blk, 0, stream>>>(
      partA, partA + 8388608, bd, x, ln_g, ln_b, h, hb);

  // mlpb = gelu(h @ w1^T + b1)
  gemm256<EPI_GELU><<<dim3(32, 16, 1), blk512, 131072, stream>>>(
      hb, w1b, b1, mlpb, 8192, 2048, 2048, 2048, 8192, 0, 0, 0, 1.f);

  // mlp2, split-K=2: partM[z] = mlpb[:, z*4096:+4096] @ w2^T-slice
  gemm256<EPI_SCORES><<<dim3(8, 16, 2), blk512, 131072, stream>>>(
      mlpb, w2b, nullptr, partM0, 2048, 4096, 8192, 8192, 2048,
      4096, 4096, (long)(201 * MB / 4), 1.f);
  // out = partM0 + partM1 + b2 + h
  reduce2<<<4096, blk, 0, stream>>>(partM0, partM1, b2, h, out);
}

// Round 16
// 582.094 us; speedup vs baseline: 1.2158x; 1.0476x over previous
//
#include <hip/hip_runtime.h>
#include <math.h>

// PhiDecoderLayer on MI355X. B=2, S=2048, E=2048, MLP=8192, fp32 in/out.
// Round 16: r15 (610us) with gemm_bt double-buffered: per K-tile the block
// reads ONLY the current buffer and writes ONLY the other (stage for kt+1
// issued at tile start, drains under the 32 MFMAs), one vmcnt(0)+barrier per
// tile. Region-disjoint by construction -> no intra-tile races possible.
// gemm256 and all other kernels unchanged from r15.

#define SEQ 2048
#define EMB 2048
#define MLPD 8192

typedef __attribute__((ext_vector_type(8))) short short8;
typedef __attribute__((ext_vector_type(4))) float floatx4;
typedef unsigned short ushort;

__device__ __forceinline__ short f2bf(float f) {
  union { float f; unsigned u; } v; v.f = f;
  unsigned r = v.u + 0x7FFFu + ((v.u >> 16) & 1u);
  return (short)(r >> 16);
}
__device__ __forceinline__ float bf2f(ushort u) {
  union { unsigned u; float f; } v; v.u = ((unsigned)u) << 16;
  return v.f;
}

// async global->LDS, 16B per lane. LDS dest = wave-uniform base + lane*16.
__device__ __forceinline__ void gload16(const ushort* g, ushort* l) {
  __builtin_amdgcn_global_load_lds(
      (__attribute__((address_space(1))) void*)g,
      (__attribute__((address_space(3))) void*)(unsigned)(unsigned long)l,
      16, 0, 0);
}

enum { EPI_QKV = 0, EPI_SCORES = 1, EPI_PV = 2, EPI_GELU = 4,
       EPI_VT = 5, EPI_SBF16 = 6 };

// ============================================================================
// 256x256 tile, BK=64, 8 waves — r10 structure (one barrier per phase).
// ============================================================================
template<int EPI>
__global__ __launch_bounds__(512, 2)
void gemm256(const ushort* __restrict__ A, const ushort* __restrict__ B,
             const float* __restrict__ bias, void* __restrict__ Cp,
             int N, int K, int lda, int ldb, int ldc,
             long sA, long sB, long sC, float scale)
{
  extern __shared__ ushort lds[];   // 65536 ushorts = 128 KiB
  const int t = threadIdx.x;
  const int lane = t & 63, w = t >> 6;
  const int wm = w >> 2, wn = w & 3;
  const long bm = (long)blockIdx.y * 256;
  const long bn = (long)blockIdx.x * 256;
  A += (long)blockIdx.z * sA;
  B += (long)blockIdx.z * sB;

  const int srow = (w << 3) + (lane >> 3);
  const int gcol = (lane & 7) ^ ((lane >> 3) & 7);
  const ushort* Ab = A + (bm + srow) * (long)lda + gcol * 8;
  const ushort* Bb = B + (bn + srow) * (long)ldb + gcol * 8;
  ushort* lw = lds + (w << 9);

#define STG_A0(LOFF, KK) do { gload16(Ab + (KK), lw + (LOFF)); \
    gload16(Ab + 64L * lda + (KK), lw + (LOFF) + 4096); } while (0)
#define STG_A1(LOFF, KK) do { gload16(Ab + 128L * lda + (KK), lw + (LOFF)); \
    gload16(Ab + 192L * lda + (KK), lw + (LOFF) + 4096); } while (0)
#define STG_B0(LOFF, KK) do { gload16(Bb + (KK), lw + (LOFF)); \
    gload16(Bb + 64L * ldb + (KK), lw + (LOFF) + 4096); } while (0)
#define STG_B1(LOFF, KK) do { gload16(Bb + 128L * ldb + (KK), lw + (LOFF)); \
    gload16(Bb + 192L * ldb + (KK), lw + (LOFF) + 4096); } while (0)

  const int l15 = lane & 15, q = lane >> 4, swz = l15 & 7;
  const int kx0 = (q ^ swz) << 3;
  const int kx1 = ((4 + q) ^ swz) << 3;
  const int arow = (wm << 13) + l15 * 64;
  const int brow = 16384 + ((wn >> 1) << 13) + ((wn & 1) << 12) + l15 * 64;

  floatx4 acc[8][4];
#pragma unroll
  for (int m = 0; m < 8; ++m)
#pragma unroll
    for (int n = 0; n < 4; ++n) acc[m][n] = (floatx4)0.0f;

  short8 A0[4], A1[4], B0[4], B1[4];

#define LDS8(IDX) (*(const short8*)&lds[IDX])
#define RD_ALK0(CB) do { _Pragma("unroll") for (int mf = 0; mf < 4; ++mf) \
    A0[mf] = LDS8((CB) + arow + mf * 1024 + kx0); } while (0)
#define RD_ALK1(CB) do { _Pragma("unroll") for (int mf = 0; mf < 4; ++mf) \
    A1[mf] = LDS8((CB) + arow + mf * 1024 + kx1); } while (0)
#define RD_AHK0(CB) do { _Pragma("unroll") for (int mf = 0; mf < 4; ++mf) \
    A0[mf] = LDS8((CB) + arow + (4 + mf) * 1024 + kx0); } while (0)
#define RD_AHK1(CB) do { _Pragma("unroll") for (int mf = 0; mf < 4; ++mf) \
    A1[mf] = LDS8((CB) + arow + (4 + mf) * 1024 + kx1); } while (0)
#define RD_BK0(CB) do { _Pragma("unroll") for (int nf = 0; nf < 4; ++nf) \
    B0[nf] = LDS8((CB) + brow + nf * 1024 + kx0); } while (0)
#define RD_BK1(CB) do { _Pragma("unroll") for (int nf = 0; nf < 4; ++nf) \
    B1[nf] = LDS8((CB) + brow + nf * 1024 + kx1); } while (0)

#define MMA16(MO, AX, BX) do {                                            \
    __builtin_amdgcn_s_setprio(1);                                        \
    _Pragma("unroll") for (int mf = 0; mf < 4; ++mf)                      \
      _Pragma("unroll") for (int nf = 0; nf < 4; ++nf)                    \
        acc[(MO)+mf][nf] = __builtin_amdgcn_mfma_f32_16x16x32_bf16(       \
            AX[mf], BX[nf], acc[(MO)+mf][nf], 0, 0, 0);                   \
    __builtin_amdgcn_s_setprio(0);                                        \
  } while (0)

#define BARR() __builtin_amdgcn_s_barrier()
#define VMC4  asm volatile("s_waitcnt vmcnt(4)" ::: "memory")

#define KTILE(CB, NB, K1, K2) do {                                        \
    RD_ALK0(CB); RD_BK0(CB); STG_A0((NB) + 0, K1);                        \
    MMA16(0, A0, B0); BARR();                                             \
    RD_ALK1(CB); RD_BK1(CB); STG_A1((NB) + 8192, K1);                     \
    MMA16(0, A1, B1); BARR();                                             \
    RD_AHK0(CB); STG_B0((CB) + 16384, K2);                                \
    MMA16(4, A0, B0); BARR();                                             \
    RD_AHK1(CB); STG_B1((CB) + 24576, K2);                                \
    MMA16(4, A1, B1); VMC4; BARR();                                       \
  } while (0)

  STG_A0(0, 0);              STG_A1(8192, 0);
  STG_B0(16384, 0);          STG_B1(24576, 0);
  {
    const int k1p = (K > 64) ? 64 : 0;
    STG_B0(32768 + 16384, k1p);
    STG_B1(32768 + 24576, k1p);
  }
  asm volatile("s_waitcnt vmcnt(4)" ::: "memory");
  BARR();

  const int NT = K >> 6;
  for (int kt = 0; kt < NT; kt += 2) {
    const int k1 = ((kt + 1 < NT) ? kt + 1 : NT - 1) << 6;
    const int k2 = ((kt + 2 < NT) ? kt + 2 : NT - 1) << 6;
    const int k3 = ((kt + 3 < NT) ? kt + 3 : NT - 1) << 6;
    KTILE(0,     32768, k1, k2);
    KTILE(32768, 0,     k2, k3);
  }
  asm volatile("s_waitcnt vmcnt(0)" ::: "memory");
#undef KTILE
#undef MMA16
#undef RD_ALK0
#undef RD_ALK1
#undef RD_AHK0
#undef RD_AHK1
#undef RD_BK0
#undef RD_BK1
#undef LDS8
#undef STG_A0
#undef STG_A1
#undef STG_B0
#undef STG_B1

  const int lq = lane >> 4;
#pragma unroll
  for (int mf = 0; mf < 8; ++mf) {
#pragma unroll
    for (int nf = 0; nf < 4; ++nf) {
#pragma unroll
      for (int i = 0; i < 4; ++i) {
        const long r = bm + wm * 128 + mf * 16 + lq * 4 + i;
        const long c = bn + wn * 64 + nf * 16 + l15;
        float val = acc[mf][nf][i];
        if constexpr (EPI == EPI_QKV) {
          val += bias[c];
          ((ushort*)Cp)[r * (long)ldc + c] = (ushort)f2bf(val);
        } else if constexpr (EPI == EPI_SCORES) {  // raw f32 partial
          ((float*)Cp)[(long)blockIdx.z * sC + r * (long)ldc + c] = val * scale;
        } else {  // EPI_GELU exact
          val += bias[c];
          float g = 0.5f * val * (1.0f + erff(val * 0.70710678118f));
          ((ushort*)Cp)[r * (long)ldc + c] = (ushort)f2bf(g);
        }
      }
    }
  }
}

// ============================================================================
// 128x128 tile, BK=64, 4 waves, DOUBLE-buffered (64 KiB): per K-tile the
// block reads only CB and stages kt+1 into NB (disjoint regions -> one
// vmcnt(0)+barrier per tile, no intra-tile sync). Swizzled LDS as before.
// Used for scores (bf16 out), PV, and direct-V^T.
// ============================================================================
template<int EPI>
__global__ __launch_bounds__(256)
void gemm_bt(const ushort* __restrict__ A, const ushort* __restrict__ B,
             const float* __restrict__ bias, void* __restrict__ Cp,
             int N, int K, int lda, int ldb, int ldc,
             long sA, long sB, long sC, float scale)
{
  __shared__ ushort lds[32768];  // 64 KiB: X.A|X.B|Y.A|Y.B (8192 ushorts each)

  const int t = threadIdx.x;
  const int lane = t & 63, wid = t >> 6;
  const int wm = wid >> 1, wn = wid & 1;
  const long bm = (long)blockIdx.y * 128;
  const long bn = (long)blockIdx.x * 128;
  A += (long)blockIdx.z * sA;
  B += (long)blockIdx.z * sB;

  const int srow = (wid << 3) + (lane >> 3);            // 0..31
  const int gcol = (lane & 7) ^ ((lane >> 3) & 7);      // pre-swizzled granule
  const ushort* a0 = A + (bm + srow) * (long)lda + gcol * 8;
  const ushort* b0 = B + (bn + srow) * (long)ldb + gcol * 8;
  const int lw = (wid << 9);

#define STG(CB, KK) do { _Pragma("unroll") for (int i = 0; i < 4; ++i) {   \
    gload16(a0 + (32L * i) * lda + (KK), lds + (CB) + lw + i * 2048);      \
    gload16(b0 + (32L * i) * ldb + (KK), lds + (CB) + 8192 + lw + i * 2048); } } while (0)

  floatx4 acc[4][4];
#pragma unroll
  for (int m = 0; m < 4; ++m)
#pragma unroll
    for (int n = 0; n < 4; ++n) acc[m][n] = (floatx4)0.0f;

  const int l15 = lane & 15, q = lane >> 4, swz = l15 & 7;
  const int kx0 = (q ^ swz) << 3;
  const int kx1 = ((4 + q) ^ swz) << 3;
  const int abase = ((wm << 6) + l15) * 64;
  const int bbase = 8192 + ((wn << 6) + l15) * 64;

#define TILE(CB, NB, KK) do {                                              \
    STG(NB, KK);   /* stage next tile first: drains under this MFMA */     \
    short8 a0r[4], a1r[4], b0r[4], b1r[4];                                 \
    _Pragma("unroll") for (int m = 0; m < 4; ++m) {                        \
      a0r[m] = *(const short8*)&lds[(CB) + abase + m * 1024 + kx0];        \
      a1r[m] = *(const short8*)&lds[(CB) + abase + m * 1024 + kx1];        \
    }                                                                      \
    _Pragma("unroll") for (int n = 0; n < 4; ++n) {                        \
      b0r[n] = *(const short8*)&lds[(CB) + bbase + n * 1024 + kx0];        \
      b1r[n] = *(const short8*)&lds[(CB) + bbase + n * 1024 + kx1];        \
    }                                                                      \
    __builtin_amdgcn_s_setprio(1);                                         \
    _Pragma("unroll") for (int m = 0; m < 4; ++m)                          \
      _Pragma("unroll") for (int n = 0; n < 4; ++n) {                      \
        acc[m][n] = __builtin_amdgcn_mfma_f32_16x16x32_bf16(               \
            a0r[m], b0r[n], acc[m][n], 0, 0, 0);                           \
        acc[m][n] = __builtin_amdgcn_mfma_f32_16x16x32_bf16(               \
            a1r[m], b1r[n], acc[m][n], 0, 0, 0);                           \
      }                                                                    \
    __builtin_amdgcn_s_setprio(0);                                         \
    asm volatile("s_waitcnt vmcnt(0)" ::: "memory");                       \
    __builtin_amdgcn_s_barrier();                                          \
  } while (0)

  // prologue: stage tile0 -> X; certify
  STG(0, 0);
  asm volatile("s_waitcnt vmcnt(0)" ::: "memory");
  __builtin_amdgcn_s_barrier();

  const int NT = K >> 6;  // even for all shapes (32 or 64)
  for (int kt = 0; kt < NT; kt += 2) {
    const int k1 = ((kt + 1 < NT) ? kt + 1 : NT - 1) << 6;  // clamped tail
    const int k2 = ((kt + 2 < NT) ? kt + 2 : NT - 1) << 6;
    TILE(0,     16384, k1);   // tile kt   (X); stage kt+1 -> Y
    TILE(16384, 0,     k2);   // tile kt+1 (Y); stage kt+2 -> X
  }
#undef TILE
#undef STG

  const int lq = lane >> 4;
#pragma unroll
  for (int m = 0; m < 4; ++m) {
#pragma unroll
    for (int n = 0; n < 4; ++n) {
#pragma unroll
      for (int i = 0; i < 4; ++i) {
        const long r = bm + wm * 64 + m * 16 + lq * 4 + i;
        const long c = bn + wn * 64 + n * 16 + l15;
        float val = acc[m][n][i];
        if constexpr (EPI == EPI_SBF16) {        // scores, scaled bf16
          ((ushort*)Cp)[(long)blockIdx.z * sC + r * (long)ldc + c] =
              (ushort)f2bf(val * scale);
        } else if constexpr (EPI == EPI_PV) {
          ((ushort*)Cp)[(long)blockIdx.z * sC + r * (long)ldc + c] = (ushort)f2bf(val);
        } else if constexpr (EPI == EPI_VT) {    // vT: row-bias (bv[e])
          val += bias[r];
          ((ushort*)Cp)[(long)blockIdx.z * sC + r * (long)ldc + c] = (ushort)f2bf(val);
        }
      }
    }
  }
}

// ============================================================================
// Fused conversion: all fp32->bf16 conversions + bias concat in ONE dispatch.
// ============================================================================
__global__ __launch_bounds__(256)
void cvt_all(const float* x,  ushort* xb,
             const float* wq, const float* wk, ushort* wqkb,
             const float* wv, ushort* wvb,
             const float* wd, ushort* wdb,
             const float* w1, ushort* w1b,
             const float* w2, ushort* w2b,
             const float* bq, const float* bk, float* bqk)
{
  if (blockIdx.x < 16) {
    const int i = blockIdx.x * 256 + threadIdx.x;
    bqk[i] = (i < 2048) ? bq[i] : bk[i - 2048];
  }
  const long gi = ((long)blockIdx.x * 256 + threadIdx.x) * 8;
  const float* src;
  ushort* dst;
  long off;
  if (gi < 8388608L)        { src = x;  dst = xb;             off = 0; }
  else if (gi < 12582912L)  { src = wq; dst = wqkb;           off = 8388608L; }
  else if (gi < 16777216L)  { src = wk; dst = wqkb + 4194304; off = 12582912L; }
  else if (gi < 20971520L)  { src = wv; dst = wvb;            off = 16777216L; }
  else if (gi < 25165824L)  { src = wd; dst = wdb;            off = 20971520L; }
  else if (gi < 41943040L)  { src = w1; dst = w1b;            off = 25165824L; }
  else                      { src = w2; dst = w2b;            off = 41943040L; }
  const long i = gi - off;
  float4 a = *reinterpret_cast<const float4*>(src + i);
  float4 b = *reinterpret_cast<const float4*>(src + i + 4);
  short8 v;
  v[0] = f2bf(a.x); v[1] = f2bf(a.y); v[2] = f2bf(a.z); v[3] = f2bf(a.w);
  v[4] = f2bf(b.x); v[5] = f2bf(b.y); v[6] = f2bf(b.z); v[7] = f2bf(b.w);
  *reinterpret_cast<short8*>(dst + i) = v;
}

// out = p0 + p1 + bias + res  (f32, 8 elems/thread, N=2048 columns)
__global__ __launch_bounds__(256)
void reduce2(const float* __restrict__ p0, const float* __restrict__ p1,
             const float* __restrict__ bias, const float* __restrict__ res,
             float* __restrict__ out)
{
  const long i = ((long)blockIdx.x * 256 + threadIdx.x) * 8;
  const int c = (int)(i & 2047);
  float4 a0 = *(const float4*)(p0 + i),  a1 = *(const float4*)(p0 + i + 4);
  float4 q0 = *(const float4*)(p1 + i),  q1 = *(const float4*)(p1 + i + 4);
  float4 r0 = *(const float4*)(res + i), r1 = *(const float4*)(res + i + 4);
  float4 b0 = *(const float4*)(bias + c), b1 = *(const float4*)(bias + c + 4);
  float4 o0 = {a0.x + q0.x + r0.x + b0.x, a0.y + q0.y + r0.y + b0.y,
               a0.z + q0.z + r0.z + b0.z, a0.w + q0.w + r0.w + b0.w};
  float4 o1 = {a1.x + q1.x + r1.x + b1.x, a1.y + q1.y + r1.y + b1.y,
               a1.z + q1.z + r1.z + b1.z, a1.w + q1.w + r1.w + b1.w};
  *(float4*)(out + i) = o0;
  *(float4*)(out + i + 4) = o1;
}

// row softmax over bf16 scores: [4096][2048] bf16 -> probs bf16
__global__ __launch_bounds__(256)
void softmax_rows(const ushort* __restrict__ S, ushort* __restrict__ P) {
  const long row = blockIdx.x;
  const ushort* src = S + row * 2048;
  const int t = threadIdx.x, lane = t & 63, wid = t >> 6;
  short8 raw = *reinterpret_cast<const short8*>(src + t * 8);
  float v[8];
#pragma unroll
  for (int i = 0; i < 8; ++i) v[i] = bf2f((ushort)raw[i]);
  float m = v[0];
#pragma unroll
  for (int i = 1; i < 8; ++i) m = fmaxf(m, v[i]);
#pragma unroll
  for (int o = 32; o; o >>= 1) m = fmaxf(m, __shfl_xor(m, o));
  __shared__ float rm[4], rs[4];
  if (!lane) rm[wid] = m;
  __syncthreads();
  m = fmaxf(fmaxf(rm[0], rm[1]), fmaxf(rm[2], rm[3]));
  float e[8], s = 0.f;
#pragma unroll
  for (int i = 0; i < 8; ++i) { e[i] = __expf(v[i] - m); s += e[i]; }
#pragma unroll
  for (int o = 32; o; o >>= 1) s += __shfl_xor(s, o);
  if (!lane) rs[wid] = s;
  __syncthreads();
  s = rs[0] + rs[1] + rs[2] + rs[3];
  const float inv = 1.0f / s;
  short8 wv;
#pragma unroll
  for (int i = 0; i < 8; ++i) wv[i] = f2bf(e[i] * inv);
  *reinterpret_cast<short8*>(P + row * 2048 + t * 8) = wv;
}

// layernorm of (p0 + p1 + bias + res), emitting f32 H and bf16 Hb.
__global__ __launch_bounds__(256)
void layernorm_fused(const float* __restrict__ p0, const float* __restrict__ p1,
                     const float* __restrict__ bias, const float* __restrict__ res,
                     const float* __restrict__ g, const float* __restrict__ bb,
                     float* __restrict__ H, ushort* __restrict__ Hb) {
  const long row = blockIdx.x;
  const long base = row * 2048;
  const int t = threadIdx.x, lane = t & 63, wid = t >> 6;
  const long i = base + t * 8;
  const int c0 = t * 8;
  float v[8];
  {
    float4 a0 = *(const float4*)(p0 + i),  a1 = *(const float4*)(p0 + i + 4);
    float4 q0 = *(const float4*)(p1 + i),  q1 = *(const float4*)(p1 + i + 4);
    float4 r0 = *(const float4*)(res + i), r1 = *(const float4*)(res + i + 4);
    float4 b0 = *(const float4*)(bias + c0), b1 = *(const float4*)(bias + c0 + 4);
    v[0] = a0.x + q0.x + r0.x + b0.x; v[1] = a0.y + q0.y + r0.y + b0.y;
    v[2] = a0.z + q0.z + r0.z + b0.z; v[3] = a0.w + q0.w + r0.w + b0.w;
    v[4] = a1.x + q1.x + r1.x + b1.x; v[5] = a1.y + q1.y + r1.y + b1.y;
    v[6] = a1.z + q1.z + r1.z + b1.z; v[7] = a1.w + q1.w + r1.w + b1.w;
  }
  float s = 0.f, ss = 0.f;
#pragma unroll
  for (int i2 = 0; i2 < 8; ++i2) { s += v[i2]; ss += v[i2] * v[i2]; }
#pragma unroll
  for (int o = 32; o; o >>= 1) { s += __shfl_xor(s, o); ss += __shfl_xor(ss, o); }
  __shared__ float r1s[4], r2s[4];
  if (!lane) { r1s[wid] = s; r2s[wid] = ss; }
  __syncthreads();
  s = r1s[0] + r1s[1] + r1s[2] + r1s[3];
  ss = r2s[0] + r2s[1] + r2s[2] + r2s[3];
  const float mu = s * (1.0f / 2048.0f);
  const float var = ss * (1.0f / 2048.0f) - mu * mu;
  const float inv = rsqrtf(var + 1e-5f);
  float o0[8];
  short8 wv;
#pragma unroll
  for (int i2 = 0; i2 < 8; ++i2) {
    const int c = c0 + i2;
    o0[i2] = (v[i2] - mu) * inv * g[c] + bb[c];
    wv[i2] = f2bf(o0[i2]);
  }
  float4 w0 = {o0[0], o0[1], o0[2], o0[3]}, w1 = {o0[4], o0[5], o0[6], o0[7]};
  *reinterpret_cast<float4*>(H + i) = w0;
  *reinterpret_cast<float4*>(H + i + 4) = w1;
  *reinterpret_cast<short8*>(Hb + i) = wv;
}

extern "C" void kernel_launch(void* const* d_in, const int* in_sizes, int n_in,
                              void* d_out, int out_size, void* d_ws, size_t ws_size,
                              hipStream_t stream) {
  const float* x    = (const float*)d_in[0];
  const float* wq   = (const float*)d_in[1];
  const float* bq   = (const float*)d_in[2];
  const float* wk   = (const float*)d_in[3];
  const float* bk   = (const float*)d_in[4];
  const float* wv   = (const float*)d_in[5];
  const float* bv   = (const float*)d_in[6];
  const float* wd   = (const float*)d_in[7];
  const float* bd   = (const float*)d_in[8];
  const float* ln_g = (const float*)d_in[9];
  const float* ln_b = (const float*)d_in[10];
  const float* w1   = (const float*)d_in[11];
  const float* b1   = (const float*)d_in[12];
  const float* w2   = (const float*)d_in[13];
  const float* b2   = (const float*)d_in[14];
  float* out = (float*)d_out;

  (void)hipFuncSetAttribute((const void*)&gemm256<EPI_QKV>,
      hipFuncAttributeMaxDynamicSharedMemorySize, 131072);
  (void)hipFuncSetAttribute((const void*)&gemm256<EPI_GELU>,
      hipFuncAttributeMaxDynamicSharedMemorySize, 131072);
  (void)hipFuncSetAttribute((const void*)&gemm256<EPI_SCORES>,
      hipFuncAttributeMaxDynamicSharedMemorySize, 131072);

  // ---- workspace layout (233 MiB, aliased; liveness audited) ----
  char* p = (char*)d_ws;
  const size_t MB = 1048576;
  ushort* wdb    = (ushort*)(p + 0 * MB);     // 8 MB   [dead after attn-out]
  ushort* w1b    = (ushort*)(p + 8 * MB);     // 32 MB  [dead after mlp1]
  ushort* w2b    = (ushort*)(p + 40 * MB);    // 32 MB  [live till mlp2]
  float*  bqk    = (float*) (p + 72 * MB);    // 16 KB
  ushort* xb     = (ushort*)(p + 73 * MB);    // 16 MB  [dead after vT] -> probs
  ushort* probs  = xb;
  ushort* qk     = (ushort*)(p + 89 * MB);    // 32 MB  [dead after scores]
  ushort* wqkb   = (ushort*)(p + 121 * MB);   // 16 MB  [dead after QK]
  ushort* vT     = (ushort*)(p + 121 * MB);   // 16 MB  [dead after PV]
  ushort* wvb    = (ushort*)(p + 137 * MB);   // 8 MB   [dead after vT]
  ushort* scoresb= (ushort*)(p + 137 * MB);   // 16 MB  [dead after softmax]
  float*  partA  = (float*) (p + 89 * MB);    // 64 MB (89-153) attn-out out
  ushort* mlpb   = (ushort*)(p + 89 * MB);    // 64 MB  mlp1 out
  float*  h      = (float*) (p + 153 * MB);   // 32 MB  [live till end]
  ushort* hb     = (ushort*)(p + 185 * MB);   // 16 MB  [dead after mlp1]
  ushort* ctx    = (ushort*)(p + 201 * MB);   // 16 MB  [dead after attn-out]
  float*  partM0 = (float*) (p + 0 * MB);     // 32 MB  (wdb/w1b dead)
  float*  partM1 = (float*) (p + 201 * MB);   // 32 MB  (ctx dead)

  const dim3 blk(256), blk512(512);
  const long SQ = (long)SEQ * SEQ;

  // ---- one fused conversion dispatch (7 tensors + bias concat) ----
  cvt_all<<<28672, blk, 0, stream>>>(
      x, xb, wq, wk, wqkb, wv, wvb, wd, wdb, w1, w1b, w2, w2b, bq, bk, bqk);

  // QK: [4096,2048] x [4096,2048]^T -> qk bf16 [4096][4096] (1 full round)
  gemm256<EPI_QKV><<<dim3(16, 16, 1), blk512, 131072, stream>>>(
      xb, wqkb, bqk, qk, 4096, 2048, 2048, 2048, 4096, 0, 0, 0, 1.f);

  // vT[b][e][s] = wv[e]·x[b,s] + bv[e]  (direct transposed V)
  gemm_bt<EPI_VT><<<dim3(16, 16, 2), blk, 0, stream>>>(
      wvb, xb, bv, vT, 2048, 2048, 2048, 2048, 2048,
      0, SQ, SQ, 1.f);

  // scores = q k^T / sqrt(E) per batch -> bf16
  gemm_bt<EPI_SBF16><<<dim3(16, 16, 2), blk, 0, stream>>>(
      qk, qk + 2048, nullptr, scoresb, 2048, 2048, 4096, 4096, 2048,
      2048L * 4096, 2048L * 4096, SQ, 0.022097086912079608f);

  softmax_rows<<<dim3(4096), blk, 0, stream>>>(scoresb, probs);

  // ctx = probs @ v
  gemm_bt<EPI_PV><<<dim3(16, 16, 2), blk, 0, stream>>>(
      probs, vT, nullptr, ctx, 2048, 2048, 2048, 2048, 2048,
      SQ, SQ, SQ, 1.f);

  // attn-out, split-K=2: partA[z] = ctx[:, z*1024:+1024] @ wd^T-slice
  gemm256<EPI_SCORES><<<dim3(8, 16, 2), blk512, 131072, stream>>>(
      ctx, wdb, nullptr, partA, 2048, 1024, 2048, 2048, 2048,
      1024, 1024, 8388608, 1.f);

  // h = LN(partA0 + partA1 + bd + x); hb = bf16(h)
  layernorm_fused<<<4096, blk, 0, stream>>>(
      partA, partA + 8388608, bd, x, ln_g, ln_b, h, hb);

  // mlpb = gelu(h @ w1^T + b1)
  gemm256<EPI_GELU><<<dim3(32, 16, 1), blk512, 131072, stream>>>(
      hb, w1b, b1, mlpb, 8192, 2048, 2048, 2048, 8192, 0, 0, 0, 1.f);

  // mlp2, split-K=2: partM[z] = mlpb[:, z*4096:+4096] @ w2^T-slice
  gemm256<EPI_SCORES><<<dim3(8, 16, 2), blk512, 131072, stream>>>(
      mlpb, w2b, nullptr, partM0, 2048, 4096, 8192, 8192, 2048,
      4096, 4096, (long)(201 * MB / 4), 1.f);
  // out = partM0 + partM1 + b2 + h
  reduce2<<<4096, blk, 0, stream>>>(partM0, partM1, b2, h, out);
}